// Round 1
// 581.076 us; speedup vs baseline: 1.3490x; 1.3490x over previous
//
#include <hip/hip_runtime.h>
#include <hip/hip_bf16.h>

// Problem: inputs (16384, 2048) fp32 -> reshape (g=4, N=16384, d=512).
#define NG 4
#define DD 512
#define NN 16384
#define EPSV 1e-5f
#define GRP_ELEMS ((size_t)NN * DD)      // 8388608 = 2^23
#define MAT_ELEMS ((size_t)DD * DD)      // 262144
#define KCHUNKS 8

typedef __attribute__((ext_vector_type(8))) short bf16x8;
typedef __attribute__((ext_vector_type(4))) float f32x4;

__device__ __forceinline__ ushort f2b(float f) {
    union { float f; unsigned u; } x; x.f = f;
    unsigned r = (x.u + 0x7fffu + ((x.u >> 16) & 1u)) >> 16;
    return (ushort)r;
}
__device__ __forceinline__ float b2f(ushort u) {
    union { unsigned u; float f; } x; x.u = ((unsigned)u) << 16;
    return x.f;
}
__device__ __forceinline__ void load_lds16(const ushort* g, ushort* l) {
    __builtin_amdgcn_global_load_lds(
        (const __attribute__((address_space(1))) void*)g,
        (__attribute__((address_space(3))) void*)l, 16, 0, 0);
}

// ---------------------------------------------------------------------------
// Kernel 1: column sums  cs[g*512+d] = sum_n Z[g][n][d]   (cs pre-zeroed)
__global__ __launch_bounds__(256) void colsum_kernel(const float* __restrict__ Z,
                                                     float* __restrict__ cs) {
    int c = blockIdx.x * 256 + threadIdx.x;       // 0..2047
    int a = c >> 9;
    int d = c & 511;
    const float* p = Z + (size_t)a * GRP_ELEMS + (size_t)blockIdx.y * 512 * DD + d;
    float s = 0.f;
    #pragma unroll 8
    for (int n = 0; n < 512; ++n) s += p[(size_t)n * DD];
    atomicAdd(&cs[c], s);
}

// ---------------------------------------------------------------------------
// Kernel 2: ZbT[g][d][n] = bf16(Z[g][n][d] - mu[g][d])   (64x64 transpose tiles)
__global__ __launch_bounds__(256) void convT_kernel(const float* __restrict__ Z,
                                                    const float* __restrict__ cs,
                                                    ushort* __restrict__ ZbT) {
    __shared__ float tile[64][65];
    int g = blockIdx.z;
    int n0 = blockIdx.x * 64;
    int d0 = blockIdx.y * 64;
    int t = threadIdx.x;
    int c4 = (t & 15) * 4;
    int r = t >> 4;
    float m0 = cs[g * DD + d0 + c4 + 0] * (1.f / (float)NN);
    float m1 = cs[g * DD + d0 + c4 + 1] * (1.f / (float)NN);
    float m2 = cs[g * DD + d0 + c4 + 2] * (1.f / (float)NN);
    float m3 = cs[g * DD + d0 + c4 + 3] * (1.f / (float)NN);
    const float* Zg = Z + (size_t)g * GRP_ELEMS;
    #pragma unroll
    for (int p = 0; p < 4; ++p) {
        int rr = r + p * 16;
        float4 v = *(const float4*)&Zg[(size_t)(n0 + rr) * DD + d0 + c4];
        tile[rr][c4 + 0] = v.x - m0;
        tile[rr][c4 + 1] = v.y - m1;
        tile[rr][c4 + 2] = v.z - m2;
        tile[rr][c4 + 3] = v.w - m3;
    }
    __syncthreads();
    ushort* Og = ZbT + (size_t)g * GRP_ELEMS;
    #pragma unroll
    for (int p = 0; p < 4; ++p) {
        int dl = r + p * 16;
        int nl = c4;
        ushort4 o;
        o.x = f2b(tile[nl + 0][dl]);
        o.y = f2b(tile[nl + 1][dl]);
        o.z = f2b(tile[nl + 2][dl]);
        o.w = f2b(tile[nl + 3][dl]);
        *(ushort4*)&Og[(size_t)(d0 + dl) * NN + n0 + nl] = o;
    }
}

// ---------------------------------------------------------------------------
// Kernel 3: Zb[g][n][d] = bf16(Z - mu)  (no transpose; may alias ZbT buffer,
// launched only after syrk has consumed ZbT)
__global__ __launch_bounds__(256) void convN_kernel(const float* __restrict__ Z,
                                                    const float* __restrict__ cs,
                                                    ushort* __restrict__ Zb) {
    size_t i4 = (size_t)blockIdx.x * 256 + threadIdx.x;
    size_t base = i4 * 4;
    int g = (int)(base >> 23);
    int d = (int)(base & 511);
    float4 v = *(const float4*)&Z[base];
    const float* c = cs + g * DD + d;
    ushort4 o;
    o.x = f2b(v.x - c[0] * (1.f / (float)NN));
    o.y = f2b(v.y - c[1] * (1.f / (float)NN));
    o.z = f2b(v.z - c[2] * (1.f / (float)NN));
    o.w = f2b(v.w - c[3] * (1.f / (float)NN));
    *(ushort4*)&Zb[base] = o;
}

// ---------------------------------------------------------------------------
// Shared MFMA GEMM:  C = A * B^T, A [M][K] bf16 (lda), B [N][K] bf16 (ldb).
// 128x128 tile / workgroup, 4 waves, each wave 64x64 = 4x4 MFMA 16x16x32.
// MODE 0: syrk partial   -> outF[(chunkY*NG+g)*MAT + m*512 + n]  (fp32)
// MODE 1: plain          -> outU bf16
// MODE 2: NS update      -> outU = bf16(1.5*Cur - 0.5*invnu*acc)
// MODE 3: output gemm    -> outF = acc * nrm^(-1/4)   (group stride GRP)
template<int MODE>
__global__ __launch_bounds__(256) void gemm_bt(
    const ushort* __restrict__ Ap, const ushort* __restrict__ Bp,
    float* __restrict__ outF, ushort* __restrict__ outU,
    const ushort* __restrict__ Curp, const float* __restrict__ nrm,
    int Mtiles, int lda, int ldb, int K, size_t grpA, size_t grpB)
{
    __shared__ __align__(16) ushort As[128 * 32];
    __shared__ __align__(16) ushort Bs[128 * 32];
    const int g = blockIdx.z;
    const int tm = (blockIdx.x % Mtiles) * 128;
    const int tn = (blockIdx.x / Mtiles) * 128;
    const int kstart = blockIdx.y * K;
    const ushort* Ag = Ap + (size_t)g * grpA;
    const ushort* Bg = Bp + (size_t)g * grpB;
    const int t = threadIdx.x;
    const int wave = t >> 6, lane = t & 63;
    const int lr = lane >> 2;            // staging row within 16-row slab
    const int lc = (lane & 3) * 8;       // staging k offset (ushort)
    const int s0 = wave * 2;             // this wave's 2 slabs per operand
    const int qm = (wave & 1) * 64, qn = (wave >> 1) * 64;
    const int fm = lane & 15;            // fragment row
    const int fk = (lane >> 4) * 8;      // fragment k offset

    const ushort* a0p = Ag + (size_t)(tm + s0 * 16 + lr) * lda + lc;
    const ushort* a1p = Ag + (size_t)(tm + s0 * 16 + 16 + lr) * lda + lc;
    const ushort* b0p = Bg + (size_t)(tn + s0 * 16 + lr) * ldb + lc;
    const ushort* b1p = Bg + (size_t)(tn + s0 * 16 + 16 + lr) * ldb + lc;
    ushort* lA0 = As + s0 * 512;
    ushort* lA1 = As + s0 * 512 + 512;
    ushort* lB0 = Bs + s0 * 512;
    ushort* lB1 = Bs + s0 * 512 + 512;

    f32x4 acc[4][4] = {};
    for (int k0 = kstart; k0 < kstart + K; k0 += 32) {
        load_lds16(a0p + k0, lA0);
        load_lds16(a1p + k0, lA1);
        load_lds16(b0p + k0, lB0);
        load_lds16(b1p + k0, lB1);
        __syncthreads();                 // drains vmcnt -> LDS valid
        bf16x8 af[4], bfr[4];
        #pragma unroll
        for (int i = 0; i < 4; ++i) {
            af[i]  = *(const bf16x8*)&As[(qm + i * 16 + fm) * 32 + fk];
            bfr[i] = *(const bf16x8*)&Bs[(qn + i * 16 + fm) * 32 + fk];
        }
        #pragma unroll
        for (int i = 0; i < 4; ++i)
            #pragma unroll
            for (int j = 0; j < 4; ++j)
                acc[i][j] = __builtin_amdgcn_mfma_f32_16x16x32_bf16(
                    af[i], bfr[j], acc[i][j], 0, 0, 0);
        __syncthreads();                 // LDS reuse guard
    }

    // C/D layout (m89-verified): col = lane&15, row = (lane>>4)*4 + reg
    const int cn0 = tn + qn + fm;
    const int cm0 = tm + qm + (lane >> 4) * 4;
    if (MODE == 0) {
        float* O = outF + (size_t)(blockIdx.y * NG + g) * MAT_ELEMS;
        #pragma unroll
        for (int i = 0; i < 4; ++i)
            #pragma unroll
            for (int r = 0; r < 4; ++r) {
                size_t row = (size_t)(cm0 + i * 16 + r) * DD;
                #pragma unroll
                for (int j = 0; j < 4; ++j)
                    O[row + cn0 + j * 16] = acc[i][j][r];
            }
    } else if (MODE == 1) {
        ushort* O = outU + (size_t)g * MAT_ELEMS;
        #pragma unroll
        for (int i = 0; i < 4; ++i)
            #pragma unroll
            for (int r = 0; r < 4; ++r) {
                size_t row = (size_t)(cm0 + i * 16 + r) * DD;
                #pragma unroll
                for (int j = 0; j < 4; ++j)
                    O[row + cn0 + j * 16] = f2b(acc[i][j][r]);
            }
    } else if (MODE == 2) {
        const ushort* C = Curp + (size_t)g * MAT_ELEMS;
        ushort* O = outU + (size_t)g * MAT_ELEMS;
        float sc = 0.5f * rsqrtf(nrm[g]);        // 0.5/nu
        #pragma unroll
        for (int i = 0; i < 4; ++i)
            #pragma unroll
            for (int r = 0; r < 4; ++r) {
                size_t row = (size_t)(cm0 + i * 16 + r) * DD;
                #pragma unroll
                for (int j = 0; j < 4; ++j) {
                    size_t off = row + cn0 + j * 16;
                    O[off] = f2b(1.5f * b2f(C[off]) - sc * acc[i][j][r]);
                }
            }
    } else {
        float* O = outF + (size_t)g * GRP_ELEMS;
        float sc = rsqrtf(sqrtf(nrm[g]));        // nu^(-1/2), nu = sqrt(nrm)
        #pragma unroll
        for (int i = 0; i < 4; ++i)
            #pragma unroll
            for (int r = 0; r < 4; ++r) {
                size_t row = (size_t)(cm0 + i * 16 + r) * DD;
                #pragma unroll
                for (int j = 0; j < 4; ++j)
                    O[row + cn0 + j * 16] = sc * acc[i][j][r];
            }
    }
}

// ---------------------------------------------------------------------------
// Kernel 5: reduce split-K partials, add eps*I, emit bf16 S + per-block
// Frobenius^2 partial (NO atomics: 16384 same-line device atomics cost 211us).
__global__ __launch_bounds__(256) void reduce_fin(const float* __restrict__ Sp,
                                                  ushort* __restrict__ Sb,
                                                  float* __restrict__ nrmP) {
    __shared__ float wsum[4];
    int g = blockIdx.z;
    int idx = blockIdx.x * 256 + threadIdx.x;
    float v = 0.f;
    #pragma unroll
    for (int c = 0; c < KCHUNKS; ++c)
        v += Sp[(size_t)(c * NG + g) * MAT_ELEMS + idx];
    int i = idx >> 9, j = idx & 511;
    if (i == j) v += EPSV;
    Sb[(size_t)g * MAT_ELEMS + idx] = f2b(v);
    float ss = v * v;
    #pragma unroll
    for (int o = 32; o; o >>= 1) ss += __shfl_down(ss, o, 64);
    if ((threadIdx.x & 63) == 0) wsum[threadIdx.x >> 6] = ss;
    __syncthreads();
    if (threadIdx.x == 0)
        nrmP[(size_t)g * 1024 + blockIdx.x] = wsum[0] + wsum[1] + wsum[2] + wsum[3];
}

// ---------------------------------------------------------------------------
// Kernel 5b: fold the 1024 per-block partials into nrm[g]. 4 blocks, ~2us.
__global__ __launch_bounds__(256) void nrm_fin(const float* __restrict__ nrmP,
                                               float* __restrict__ nrm) {
    __shared__ float wsum[4];
    int g = blockIdx.x;
    float s = 0.f;
    #pragma unroll
    for (int p = 0; p < 4; ++p)
        s += nrmP[(size_t)g * 1024 + p * 256 + threadIdx.x];
    #pragma unroll
    for (int o = 32; o; o >>= 1) s += __shfl_down(s, o, 64);
    if ((threadIdx.x & 63) == 0) wsum[threadIdx.x >> 6] = s;
    __syncthreads();
    if (threadIdx.x == 0) nrm[g] = wsum[0] + wsum[1] + wsum[2] + wsum[3];
}

// ---------------------------------------------------------------------------
// Kernel 6: B1 = bf16(1.5*I - 0.5*invnu*S)   (folds NS iteration 1, B0 = I)
__global__ __launch_bounds__(256) void initB_kernel(const ushort* __restrict__ Sb,
                                                    const float* __restrict__ nrm,
                                                    ushort* __restrict__ B0) {
    int g = blockIdx.z;
    int idx = blockIdx.x * 256 + threadIdx.x;
    int i = idx >> 9, j = idx & 511;
    float invnu = rsqrtf(nrm[g]);
    size_t off = (size_t)g * MAT_ELEMS + idx;
    float v = ((i == j) ? 1.5f : 0.f) - 0.5f * invnu * b2f(Sb[off]);
    B0[off] = f2b(v);
}

// ---------------------------------------------------------------------------
extern "C" void kernel_launch(void* const* d_in, const int* in_sizes, int n_in,
                              void* d_out, int out_size, void* d_ws, size_t ws_size,
                              hipStream_t stream) {
    const float* Z = (const float*)d_in[0];
    float* out = (float*)d_out;
    float* ws = (float*)d_ws;

    float* cs   = ws;                                      // 2048 fp32
    float* nrm  = ws + 2048;                               // 4 fp32 (pad to 64)
    float* nrmP = ws + 2112;                               // 4096 fp32 partials
    ushort* Zbuf = (ushort*)(ws + 8192);                   // ZbT then Zb (aliased), 67 MB
    float* Spart = ws + 8192 + (NG * GRP_ELEMS / 2);       // 8*4*MAT fp32 (33.5 MB)
    ushort* Sb = (ushort*)(Spart + (size_t)KCHUNKS * NG * MAT_ELEMS);
    ushort* B0 = Sb + NG * MAT_ELEMS;
    ushort* B1 = B0 + NG * MAT_ELEMS;
    ushort* Pb = B1 + NG * MAT_ELEMS;
    ushort* Qb = Pb + NG * MAT_ELEMS;

    hipMemsetAsync(ws, 0, 2048 * sizeof(float), stream);   // cs only (nrm is stored, not accumulated)

    colsum_kernel<<<dim3(8, 32), 256, 0, stream>>>(Z, cs);
    convT_kernel<<<dim3(256, 8, NG), 256, 0, stream>>>(Z, cs, Zbuf);

    // S partials: 4x (512,512,16384) syrk as gemm_bt over ZbT, split-K=8
    gemm_bt<0><<<dim3(16, KCHUNKS, NG), 256, 0, stream>>>(
        Zbuf, Zbuf, Spart, nullptr, nullptr, nullptr,
        4, NN, NN, NN / KCHUNKS, GRP_ELEMS, GRP_ELEMS);

    reduce_fin<<<dim3(1024, 1, NG), 256, 0, stream>>>(Spart, Sb, nrmP);
    nrm_fin<<<dim3(NG), 256, 0, stream>>>(nrmP, nrm);

    convN_kernel<<<dim3(32768), 256, 0, stream>>>(Z, cs, Zbuf);  // after syrk: alias OK

    initB_kernel<<<dim3(1024, 1, NG), 256, 0, stream>>>(Sb, nrm, B0);

    // NS iterations 2..5 (all operands symmetric -> A*B^T form everywhere)
    ushort* cur = B0; ushort* nxt = B1;
    for (int it = 0; it < 4; ++it) {
        gemm_bt<1><<<dim3(16, 1, NG), 256, 0, stream>>>(
            cur, cur, nullptr, Pb, nullptr, nullptr, 4, DD, DD, DD, MAT_ELEMS, MAT_ELEMS);
        gemm_bt<1><<<dim3(16, 1, NG), 256, 0, stream>>>(
            Pb, cur, nullptr, Qb, nullptr, nullptr, 4, DD, DD, DD, MAT_ELEMS, MAT_ELEMS);
        gemm_bt<2><<<dim3(16, 1, NG), 256, 0, stream>>>(
            Qb, Sb, nullptr, nxt, cur, nrm, 4, DD, DD, DD, MAT_ELEMS, MAT_ELEMS);
        ushort* tmp = cur; cur = nxt; nxt = tmp;
    }

    // out[g][n][i] = (Zc . Bfinal_row_i) * nrm^(-1/4)
    gemm_bt<3><<<dim3(512, 1, NG), 256, 0, stream>>>(
        Zbuf, cur, out, nullptr, nullptr, nrm, 128, DD, DD, DD, GRP_ELEMS, MAT_ELEMS);
}

// Round 2
// 553.092 us; speedup vs baseline: 1.4173x; 1.0506x over previous
//
#include <hip/hip_runtime.h>
#include <hip/hip_bf16.h>

// Problem: inputs (16384, 2048) fp32 -> reshape (g=4, N=16384, d=512).
#define NG 4
#define DD 512
#define NN 16384
#define EPSV 1e-5f
#define GRP_ELEMS ((size_t)NN * DD)      // 8388608 = 2^23
#define MAT_ELEMS ((size_t)DD * DD)      // 262144
#define KCHUNKS 8

typedef __attribute__((ext_vector_type(8))) short bf16x8;
typedef __attribute__((ext_vector_type(4))) float f32x4;

__device__ __forceinline__ ushort f2b(float f) {
    union { float f; unsigned u; } x; x.f = f;
    unsigned r = (x.u + 0x7fffu + ((x.u >> 16) & 1u)) >> 16;
    return (ushort)r;
}
__device__ __forceinline__ float b2f(ushort u) {
    union { unsigned u; float f; } x; x.u = ((unsigned)u) << 16;
    return x.f;
}
__device__ __forceinline__ void load_lds16(const ushort* g, ushort* l) {
    __builtin_amdgcn_global_load_lds(
        (const __attribute__((address_space(1))) void*)g,
        (__attribute__((address_space(3))) void*)l, 16, 0, 0);
}

// ---------------------------------------------------------------------------
// Kernel 1: single pass over Z. Emits UNCENTERED bf16 in both layouts
// (ZbT[g][d][n] via 64x64 LDS transpose, Zb[g][n][d] straight from registers)
// and per-(g,nblk) column-sum partials (atomic-free).
// Centering is applied algebraically downstream: S = Z~tZ~ - N mu mu^T.
__global__ __launch_bounds__(256) void convT_kernel(const float* __restrict__ Z,
                                                    ushort* __restrict__ ZbT,
                                                    ushort* __restrict__ Zb,
                                                    float* __restrict__ csP) {
    __shared__ float tile[64][65];
    int g = blockIdx.z;
    int n0 = blockIdx.x * 64;
    int d0 = blockIdx.y * 64;
    int t = threadIdx.x;
    int c4 = (t & 15) * 4;
    int r = t >> 4;
    const float* Zg = Z + (size_t)g * GRP_ELEMS;
    ushort* ZbG = Zb + (size_t)g * GRP_ELEMS;
    #pragma unroll
    for (int p = 0; p < 4; ++p) {
        int rr = r + p * 16;
        float4 v = *(const float4*)&Zg[(size_t)(n0 + rr) * DD + d0 + c4];
        tile[rr][c4 + 0] = v.x;
        tile[rr][c4 + 1] = v.y;
        tile[rr][c4 + 2] = v.z;
        tile[rr][c4 + 3] = v.w;
        ushort4 o;
        o.x = f2b(v.x); o.y = f2b(v.y); o.z = f2b(v.z); o.w = f2b(v.w);
        *(ushort4*)&ZbG[(size_t)(n0 + rr) * DD + d0 + c4] = o;
    }
    __syncthreads();
    ushort* Og = ZbT + (size_t)g * GRP_ELEMS;
    #pragma unroll
    for (int p = 0; p < 4; ++p) {
        int dl = r + p * 16;
        int nl = c4;
        ushort4 o;
        o.x = f2b(tile[nl + 0][dl]);
        o.y = f2b(tile[nl + 1][dl]);
        o.z = f2b(tile[nl + 2][dl]);
        o.w = f2b(tile[nl + 3][dl]);
        *(ushort4*)&Og[(size_t)(d0 + dl) * NN + n0 + nl] = o;
    }
    // column partial sums over this block's 64 rows (fp32, from LDS tile)
    if (t < 64) {
        float s = 0.f;
        #pragma unroll 8
        for (int n = 0; n < 64; ++n) s += tile[n][t];
        csP[((size_t)g * 256 + blockIdx.x) * 512 + d0 + t] = s;
    }
}

// ---------------------------------------------------------------------------
// Kernel 1b: fold 256 per-nblk partials -> column MEANS cs[g*512+d].
__global__ __launch_bounds__(256) void colsum_fin(const float* __restrict__ csP,
                                                  float* __restrict__ cs) {
    int c = blockIdx.x * 256 + threadIdx.x;   // 0..2047
    int g = c >> 9, d = c & 511;
    const float* p = csP + (size_t)g * 256 * 512 + d;
    float s = 0.f;
    #pragma unroll 8
    for (int b = 0; b < 256; ++b) s += p[(size_t)b * 512];
    cs[c] = s * (1.f / (float)NN);            // store the mean
}

// ---------------------------------------------------------------------------
// Shared MFMA GEMM:  C = A * B^T, A [M][K] bf16 (lda), B [N][K] bf16 (ldb).
// 128x128 tile / workgroup, 4 waves, each wave 64x64 = 4x4 MFMA 16x16x32.
// MODE 0: syrk partial   -> outF[(chunkY*NG+g)*MAT + m*512 + n]  (fp32)
// MODE 1: plain          -> outU bf16
// MODE 2: NS update      -> outU = bf16(1.5*Cur - 0.5*invnu*acc)
// MODE 3: output gemm    -> outF = (acc - bmu[col]) * nrm^(-1/4)
template<int MODE>
__global__ __launch_bounds__(256) void gemm_bt(
    const ushort* __restrict__ Ap, const ushort* __restrict__ Bp,
    float* __restrict__ outF, ushort* __restrict__ outU,
    const ushort* __restrict__ Curp, const float* __restrict__ nrm,
    const float* __restrict__ bmup,
    int Mtiles, int lda, int ldb, int K, size_t grpA, size_t grpB)
{
    __shared__ __align__(16) ushort As[128 * 32];
    __shared__ __align__(16) ushort Bs[128 * 32];
    const int g = blockIdx.z;
    const int tm = (blockIdx.x % Mtiles) * 128;
    const int tn = (blockIdx.x / Mtiles) * 128;
    const int kstart = blockIdx.y * K;
    const ushort* Ag = Ap + (size_t)g * grpA;
    const ushort* Bg = Bp + (size_t)g * grpB;
    const int t = threadIdx.x;
    const int wave = t >> 6, lane = t & 63;
    const int lr = lane >> 2;            // staging row within 16-row slab
    const int lc = (lane & 3) * 8;       // staging k offset (ushort)
    const int s0 = wave * 2;             // this wave's 2 slabs per operand
    const int qm = (wave & 1) * 64, qn = (wave >> 1) * 64;
    const int fm = lane & 15;            // fragment row
    const int fk = (lane >> 4) * 8;      // fragment k offset

    const ushort* a0p = Ag + (size_t)(tm + s0 * 16 + lr) * lda + lc;
    const ushort* a1p = Ag + (size_t)(tm + s0 * 16 + 16 + lr) * lda + lc;
    const ushort* b0p = Bg + (size_t)(tn + s0 * 16 + lr) * ldb + lc;
    const ushort* b1p = Bg + (size_t)(tn + s0 * 16 + 16 + lr) * ldb + lc;
    ushort* lA0 = As + s0 * 512;
    ushort* lA1 = As + s0 * 512 + 512;
    ushort* lB0 = Bs + s0 * 512;
    ushort* lB1 = Bs + s0 * 512 + 512;

    f32x4 acc[4][4] = {};
    for (int k0 = kstart; k0 < kstart + K; k0 += 32) {
        load_lds16(a0p + k0, lA0);
        load_lds16(a1p + k0, lA1);
        load_lds16(b0p + k0, lB0);
        load_lds16(b1p + k0, lB1);
        __syncthreads();                 // drains vmcnt -> LDS valid
        bf16x8 af[4], bfr[4];
        #pragma unroll
        for (int i = 0; i < 4; ++i) {
            af[i]  = *(const bf16x8*)&As[(qm + i * 16 + fm) * 32 + fk];
            bfr[i] = *(const bf16x8*)&Bs[(qn + i * 16 + fm) * 32 + fk];
        }
        #pragma unroll
        for (int i = 0; i < 4; ++i)
            #pragma unroll
            for (int j = 0; j < 4; ++j)
                acc[i][j] = __builtin_amdgcn_mfma_f32_16x16x32_bf16(
                    af[i], bfr[j], acc[i][j], 0, 0, 0);
        __syncthreads();                 // LDS reuse guard
    }

    // C/D layout (m89-verified): col = lane&15, row = (lane>>4)*4 + reg
    const int cn0 = tn + qn + fm;
    const int cm0 = tm + qm + (lane >> 4) * 4;
    if (MODE == 0) {
        float* O = outF + (size_t)(blockIdx.y * NG + g) * MAT_ELEMS;
        #pragma unroll
        for (int i = 0; i < 4; ++i)
            #pragma unroll
            for (int r = 0; r < 4; ++r) {
                size_t row = (size_t)(cm0 + i * 16 + r) * DD;
                #pragma unroll
                for (int j = 0; j < 4; ++j)
                    O[row + cn0 + j * 16] = acc[i][j][r];
            }
    } else if (MODE == 1) {
        ushort* O = outU + (size_t)g * MAT_ELEMS;
        #pragma unroll
        for (int i = 0; i < 4; ++i)
            #pragma unroll
            for (int r = 0; r < 4; ++r) {
                size_t row = (size_t)(cm0 + i * 16 + r) * DD;
                #pragma unroll
                for (int j = 0; j < 4; ++j)
                    O[row + cn0 + j * 16] = f2b(acc[i][j][r]);
            }
    } else if (MODE == 2) {
        const ushort* C = Curp + (size_t)g * MAT_ELEMS;
        ushort* O = outU + (size_t)g * MAT_ELEMS;
        float sc = 0.5f * rsqrtf(nrm[g]);        // 0.5/nu
        #pragma unroll
        for (int i = 0; i < 4; ++i)
            #pragma unroll
            for (int r = 0; r < 4; ++r) {
                size_t row = (size_t)(cm0 + i * 16 + r) * DD;
                #pragma unroll
                for (int j = 0; j < 4; ++j) {
                    size_t off = row + cn0 + j * 16;
                    O[off] = f2b(1.5f * b2f(C[off]) - sc * acc[i][j][r]);
                }
            }
    } else {
        float* O = outF + (size_t)g * GRP_ELEMS;
        float sc = rsqrtf(sqrtf(nrm[g]));        // nu^(-1/2), nu = sqrt(nrm)
        const float* bm = bmup + g * DD;
        float bmj[4];
        #pragma unroll
        for (int j = 0; j < 4; ++j) bmj[j] = bm[cn0 + j * 16];
        #pragma unroll
        for (int i = 0; i < 4; ++i)
            #pragma unroll
            for (int r = 0; r < 4; ++r) {
                size_t row = (size_t)(cm0 + i * 16 + r) * DD;
                #pragma unroll
                for (int j = 0; j < 4; ++j)
                    O[row + cn0 + j * 16] = sc * (acc[i][j][r] - bmj[j]);
            }
    }
}

// ---------------------------------------------------------------------------
// Kernel 5: reduce split-K partials, apply mean correction (-N mu_i mu_j),
// add eps*I, emit bf16 S + per-block Frobenius^2 partial (NO atomics).
__global__ __launch_bounds__(256) void reduce_fin(const float* __restrict__ Sp,
                                                  const float* __restrict__ cs,
                                                  ushort* __restrict__ Sb,
                                                  float* __restrict__ nrmP) {
    __shared__ float wsum[4];
    int g = blockIdx.z;
    int idx = blockIdx.x * 256 + threadIdx.x;
    float v = 0.f;
    #pragma unroll
    for (int c = 0; c < KCHUNKS; ++c)
        v += Sp[(size_t)(c * NG + g) * MAT_ELEMS + idx];
    int i = idx >> 9, j = idx & 511;
    v -= (float)NN * cs[g * DD + i] * cs[g * DD + j];   // S = G - N mu mu^T
    if (i == j) v += EPSV;
    Sb[(size_t)g * MAT_ELEMS + idx] = f2b(v);
    float ss = v * v;
    #pragma unroll
    for (int o = 32; o; o >>= 1) ss += __shfl_down(ss, o, 64);
    if ((threadIdx.x & 63) == 0) wsum[threadIdx.x >> 6] = ss;
    __syncthreads();
    if (threadIdx.x == 0)
        nrmP[(size_t)g * 1024 + blockIdx.x] = wsum[0] + wsum[1] + wsum[2] + wsum[3];
}

// ---------------------------------------------------------------------------
// Kernel 5b: fold the 1024 per-block partials into nrm[g]. 4 blocks, ~2us.
__global__ __launch_bounds__(256) void nrm_fin(const float* __restrict__ nrmP,
                                               float* __restrict__ nrm) {
    __shared__ float wsum[4];
    int g = blockIdx.x;
    float s = 0.f;
    #pragma unroll
    for (int p = 0; p < 4; ++p)
        s += nrmP[(size_t)g * 1024 + p * 256 + threadIdx.x];
    #pragma unroll
    for (int o = 32; o; o >>= 1) s += __shfl_down(s, o, 64);
    if ((threadIdx.x & 63) == 0) wsum[threadIdx.x >> 6] = s;
    __syncthreads();
    if (threadIdx.x == 0) nrm[g] = wsum[0] + wsum[1] + wsum[2] + wsum[3];
}

// ---------------------------------------------------------------------------
// Kernel 6: B1 = bf16(1.5*I - 0.5*invnu*S)   (folds NS iteration 1, B0 = I)
__global__ __launch_bounds__(256) void initB_kernel(const ushort* __restrict__ Sb,
                                                    const float* __restrict__ nrm,
                                                    ushort* __restrict__ B0) {
    int g = blockIdx.z;
    int idx = blockIdx.x * 256 + threadIdx.x;
    int i = idx >> 9, j = idx & 511;
    float invnu = rsqrtf(nrm[g]);
    size_t off = (size_t)g * MAT_ELEMS + idx;
    float v = ((i == j) ? 1.5f : 0.f) - 0.5f * invnu * b2f(Sb[off]);
    B0[off] = f2b(v);
}

// ---------------------------------------------------------------------------
// Kernel 7: bmu[g][i] = sum_d B[g][i][d] * mu[g][d]  (wave-per-row, coalesced)
__global__ __launch_bounds__(256) void bmu_kernel(const ushort* __restrict__ B,
                                                  const float* __restrict__ cs,
                                                  float* __restrict__ bmu) {
    int g = blockIdx.z;
    int wave = threadIdx.x >> 6, lane = threadIdx.x & 63;
    int i = blockIdx.x * 4 + wave;
    const ushort* Bg = B + (size_t)g * MAT_ELEMS + (size_t)i * DD + lane * 8;
    const float* mu = cs + g * DD + lane * 8;
    ushort4 u0 = *(const ushort4*)(Bg);
    ushort4 u1 = *(const ushort4*)(Bg + 4);
    float s = b2f(u0.x) * mu[0] + b2f(u0.y) * mu[1]
            + b2f(u0.z) * mu[2] + b2f(u0.w) * mu[3]
            + b2f(u1.x) * mu[4] + b2f(u1.y) * mu[5]
            + b2f(u1.z) * mu[6] + b2f(u1.w) * mu[7];
    #pragma unroll
    for (int o = 32; o; o >>= 1) s += __shfl_down(s, o, 64);
    if (lane == 0) bmu[g * DD + i] = s;
}

// ---------------------------------------------------------------------------
extern "C" void kernel_launch(void* const* d_in, const int* in_sizes, int n_in,
                              void* d_out, int out_size, void* d_ws, size_t ws_size,
                              hipStream_t stream) {
    const float* Z = (const float*)d_in[0];
    float* out = (float*)d_out;
    float* ws = (float*)d_ws;

    float* cs   = ws;                        // 2048 fp32 (column MEANS)
    float* nrm  = ws + 2048;                 // 4 fp32 (padded)
    float* bmu  = ws + 2112;                 // 2048 fp32
    float* nrmP = ws + 4160;                 // 4096 fp32
    float* csP  = ws + 8256;                 // 4*256*512 = 524288 fp32
    ushort* ZbT = (ushort*)(ws + 532544);    // 64 MiB
    ushort* Zb  = (ushort*)(ws + 17309760);  // 64 MiB (own buffer, no aliasing)
    float* Spart = ws + 34086976;            // 8*4*MAT fp32 (33.5 MB)
    ushort* Sb = (ushort*)(Spart + (size_t)KCHUNKS * NG * MAT_ELEMS);
    ushort* B0 = Sb + NG * MAT_ELEMS;
    ushort* B1 = B0 + NG * MAT_ELEMS;
    ushort* Pb = B1 + NG * MAT_ELEMS;
    ushort* Qb = Pb + NG * MAT_ELEMS;

    // single pass over Z: both bf16 layouts + colsum partials (no memset needed)
    convT_kernel<<<dim3(256, 8, NG), 256, 0, stream>>>(Z, ZbT, Zb, csP);
    colsum_fin<<<dim3(8), 256, 0, stream>>>(csP, cs);

    // G partials: 4x (512,512,16384) syrk as gemm_bt over ZbT, split-K=8
    gemm_bt<0><<<dim3(16, KCHUNKS, NG), 256, 0, stream>>>(
        ZbT, ZbT, Spart, nullptr, nullptr, nullptr, nullptr,
        4, NN, NN, NN / KCHUNKS, GRP_ELEMS, GRP_ELEMS);

    reduce_fin<<<dim3(1024, 1, NG), 256, 0, stream>>>(Spart, cs, Sb, nrmP);
    nrm_fin<<<dim3(NG), 256, 0, stream>>>(nrmP, nrm);

    initB_kernel<<<dim3(1024, 1, NG), 256, 0, stream>>>(Sb, nrm, B0);

    // NS iterations 2..5 (all operands symmetric -> A*B^T form everywhere)
    ushort* cur = B0; ushort* nxt = B1;
    for (int it = 0; it < 4; ++it) {
        gemm_bt<1><<<dim3(16, 1, NG), 256, 0, stream>>>(
            cur, cur, nullptr, Pb, nullptr, nullptr, nullptr,
            4, DD, DD, DD, MAT_ELEMS, MAT_ELEMS);
        gemm_bt<1><<<dim3(16, 1, NG), 256, 0, stream>>>(
            Pb, cur, nullptr, Qb, nullptr, nullptr, nullptr,
            4, DD, DD, DD, MAT_ELEMS, MAT_ELEMS);
        gemm_bt<2><<<dim3(16, 1, NG), 256, 0, stream>>>(
            Qb, Sb, nullptr, nxt, cur, nrm, nullptr,
            4, DD, DD, DD, MAT_ELEMS, MAT_ELEMS);
        ushort* tmp = cur; cur = nxt; nxt = tmp;
    }

    // (B mu) correction vector for the uncentered output gemm
    bmu_kernel<<<dim3(128, 1, NG), 256, 0, stream>>>(cur, cs, bmu);

    // out[g][n][i] = (Z~ . Bfinal_row_i - (B mu)_i) * nrm^(-1/4)
    gemm_bt<3><<<dim3(512, 1, NG), 256, 0, stream>>>(
        Zb, cur, out, nullptr, nullptr, nrm, bmu,
        128, DD, DD, DD, GRP_ELEMS, MAT_ELEMS);
}

// Round 4
// 533.057 us; speedup vs baseline: 1.4706x; 1.0376x over previous
//
#include <hip/hip_runtime.h>
#include <hip/hip_bf16.h>

// Problem: inputs (16384, 2048) fp32 -> reshape (g=4, N=16384, d=512).
#define NG 4
#define DD 512
#define NN 16384
#define EPSV 1e-5f
#define GRP_ELEMS ((size_t)NN * DD)      // 8388608 = 2^23
#define MAT_ELEMS ((size_t)DD * DD)      // 262144
#define KCHUNKS 4

typedef __attribute__((ext_vector_type(8))) short bf16x8;
typedef __attribute__((ext_vector_type(4))) float f32x4;

__device__ __forceinline__ ushort f2b(float f) {
    union { float f; unsigned u; } x; x.f = f;
    unsigned r = (x.u + 0x7fffu + ((x.u >> 16) & 1u)) >> 16;
    return (ushort)r;
}
__device__ __forceinline__ float b2f(ushort u) {
    union { unsigned u; float f; } x; x.u = ((unsigned)u) << 16;
    return x.f;
}
__device__ __forceinline__ void load_lds16(const ushort* g, ushort* l) {
    __builtin_amdgcn_global_load_lds(
        (const __attribute__((address_space(1))) void*)g,
        (__attribute__((address_space(3))) void*)l, 16, 0, 0);
}

// ---------------------------------------------------------------------------
// Kernel 1: single pass over Z. Emits UNCENTERED bf16 in both layouts and
// per-(g,nblk) column sums. Tile 256n x 64d. The LDS tile holds the data
// ALREADY transposed as packed pairs: tileT[d][np] = bf16(Z[2np]) | bf16(Z[2np+1])<<16,
// so the drain phase is vectorized b128 reads -> 512B contiguous ZbT runs.
__global__ __launch_bounds__(256) void convT_kernel(const float* __restrict__ Z,
                                                    ushort* __restrict__ ZbT,
                                                    ushort* __restrict__ Zb,
                                                    float* __restrict__ csP) {
    __shared__ __align__(16) unsigned tileT[64][132];   // 33.8 KB, 16B-aligned rows
    int g = blockIdx.z;
    int n0 = blockIdx.x * 256;
    int d0 = blockIdx.y * 64;
    int t = threadIdx.x;
    int k4 = (t & 15) * 4;        // d-offset quad
    int q = t >> 4;               // 0..15
    const float* Zg = Z + (size_t)g * GRP_ELEMS;
    ushort* ZbG = Zb + (size_t)g * GRP_ELEMS;
    #pragma unroll
    for (int p = 0; p < 8; ++p) {
        int np = q + 16 * p;                          // n-pair index 0..127
        size_t r0 = (size_t)(n0 + 2 * np) * DD + d0 + k4;
        float4 va = *(const float4*)&Zg[r0];
        float4 vb = *(const float4*)&Zg[r0 + DD];
        ushort4 oa, ob;
        oa.x = f2b(va.x); oa.y = f2b(va.y); oa.z = f2b(va.z); oa.w = f2b(va.w);
        ob.x = f2b(vb.x); ob.y = f2b(vb.y); ob.z = f2b(vb.z); ob.w = f2b(vb.w);
        *(ushort4*)&ZbG[r0] = oa;
        *(ushort4*)&ZbG[r0 + DD] = ob;
        tileT[k4 + 0][np] = (unsigned)oa.x | ((unsigned)ob.x << 16);
        tileT[k4 + 1][np] = (unsigned)oa.y | ((unsigned)ob.y << 16);
        tileT[k4 + 2][np] = (unsigned)oa.z | ((unsigned)ob.z << 16);
        tileT[k4 + 3][np] = (unsigned)oa.w | ((unsigned)ob.w << 16);
    }
    __syncthreads();
    // drain: 64 d-rows x 512B, b128 LDS reads + 16B stores (32 lanes/row)
    ushort* Og = ZbT + (size_t)g * GRP_ELEMS;
    #pragma unroll
    for (int pp = 0; pp < 8; ++pp) {
        int ci = pp * 256 + t;
        int r = ci >> 5;                  // d row 0..63
        int c = ci & 31;                  // 16B chunk within row
        uint4 v = *(const uint4*)&tileT[r][c * 4];
        *(uint4*)&Og[(size_t)(d0 + r) * NN + n0 + c * 8] = v;
    }
    // column sums over this block's 256 rows (from bf16 tile: consistent w/ G)
    if (t < 64) {
        float s = 0.f;
        #pragma unroll 16
        for (int j = 0; j < 128; ++j) {
            unsigned u = tileT[t][j];
            s += b2f((ushort)(u & 0xffffu)) + b2f((ushort)(u >> 16));
        }
        csP[((size_t)g * 64 + blockIdx.x) * 512 + d0 + t] = s;
    }
}

// ---------------------------------------------------------------------------
// Kernel 1b: fold 64 per-nblk partials -> column MEANS cs[g*512+d].
__global__ __launch_bounds__(256) void colsum_fin(const float* __restrict__ csP,
                                                  float* __restrict__ cs) {
    int c = blockIdx.x * 256 + threadIdx.x;   // 0..2047
    int g = c >> 9, d = c & 511;
    const float* p = csP + (size_t)g * 64 * 512 + d;
    float s = 0.f;
    #pragma unroll 8
    for (int b = 0; b < 64; ++b) s += p[(size_t)b * 512];
    cs[c] = s * (1.f / (float)NN);            // store the mean
}

// ---------------------------------------------------------------------------
// Shared MFMA GEMM:  C = A * B^T, A [M][K] bf16 (lda), B [N][K] bf16 (ldb).
// 128x128 tile / workgroup, 4 waves, each wave 64x64 = 4x4 MFMA 16x16x32.
// MODE 0: syrk partial   -> outF[(chunkY*NG+g)*MAT + m*512 + n]  (fp32)
// MODE 1: plain          -> outU bf16
// MODE 2: NS update      -> outU = bf16(1.5*Cur - 0.5*invnu*acc)
// MODE 3: output gemm    -> outF = (acc - bmu[col]) * nrm^(-1/4)
// MODE 4: dual gemm      -> blockIdx.x>>4 selects {B=Bp,out=outU} / {B=Bp2,out=outU2}
template<int MODE>
__global__ __launch_bounds__(256) void gemm_bt(
    const ushort* __restrict__ Ap, const ushort* __restrict__ Bp,
    float* __restrict__ outF, ushort* __restrict__ outU,
    const ushort* __restrict__ Curp, const float* __restrict__ nrm,
    const float* __restrict__ bmup,
    const ushort* __restrict__ Bp2, ushort* __restrict__ outU2,
    int Mtiles, int lda, int ldb, int K, size_t grpA, size_t grpB)
{
    __shared__ __align__(16) ushort As[128 * 32];
    __shared__ __align__(16) ushort Bs[128 * 32];
    const int g = blockIdx.z;
    int bx = blockIdx.x;
    int half = 0;
    if (MODE == 4) { half = bx >> 4; bx &= 15; }
    const ushort* Bsrc = (MODE == 4 && half) ? Bp2 : Bp;
    ushort* Udst = (MODE == 4 && half) ? outU2 : outU;
    const int tm = (bx % Mtiles) * 128;
    const int tn = (bx / Mtiles) * 128;
    const int kstart = blockIdx.y * K;
    const ushort* Ag = Ap + (size_t)g * grpA;
    const ushort* Bg = Bsrc + (size_t)g * grpB;
    const int t = threadIdx.x;
    const int wave = t >> 6, lane = t & 63;
    const int lr = lane >> 2;            // staging row within 16-row slab
    const int lc = (lane & 3) * 8;       // staging k offset (ushort)
    const int s0 = wave * 2;             // this wave's 2 slabs per operand
    const int qm = (wave & 1) * 64, qn = (wave >> 1) * 64;
    const int fm = lane & 15;            // fragment row
    const int fk = (lane >> 4) * 8;      // fragment k offset

    const ushort* a0p = Ag + (size_t)(tm + s0 * 16 + lr) * lda + lc;
    const ushort* a1p = Ag + (size_t)(tm + s0 * 16 + 16 + lr) * lda + lc;
    const ushort* b0p = Bg + (size_t)(tn + s0 * 16 + lr) * ldb + lc;
    const ushort* b1p = Bg + (size_t)(tn + s0 * 16 + 16 + lr) * ldb + lc;
    ushort* lA0 = As + s0 * 512;
    ushort* lA1 = As + s0 * 512 + 512;
    ushort* lB0 = Bs + s0 * 512;
    ushort* lB1 = Bs + s0 * 512 + 512;

    f32x4 acc[4][4] = {};
    for (int k0 = kstart; k0 < kstart + K; k0 += 32) {
        load_lds16(a0p + k0, lA0);
        load_lds16(a1p + k0, lA1);
        load_lds16(b0p + k0, lB0);
        load_lds16(b1p + k0, lB1);
        __syncthreads();                 // drains vmcnt -> LDS valid
        bf16x8 af[4], bfr[4];
        #pragma unroll
        for (int i = 0; i < 4; ++i) {
            af[i]  = *(const bf16x8*)&As[(qm + i * 16 + fm) * 32 + fk];
            bfr[i] = *(const bf16x8*)&Bs[(qn + i * 16 + fm) * 32 + fk];
        }
        #pragma unroll
        for (int i = 0; i < 4; ++i)
            #pragma unroll
            for (int j = 0; j < 4; ++j)
                acc[i][j] = __builtin_amdgcn_mfma_f32_16x16x32_bf16(
                    af[i], bfr[j], acc[i][j], 0, 0, 0);
        __syncthreads();                 // LDS reuse guard
    }

    // C/D layout (m89-verified): col = lane&15, row = (lane>>4)*4 + reg
    const int cn0 = tn + qn + fm;
    const int cm0 = tm + qm + (lane >> 4) * 4;
    if (MODE == 0) {
        float* O = outF + (size_t)(blockIdx.y * NG + g) * MAT_ELEMS;
        #pragma unroll
        for (int i = 0; i < 4; ++i)
            #pragma unroll
            for (int r = 0; r < 4; ++r) {
                size_t row = (size_t)(cm0 + i * 16 + r) * DD;
                #pragma unroll
                for (int j = 0; j < 4; ++j)
                    O[row + cn0 + j * 16] = acc[i][j][r];
            }
    } else if (MODE == 1 || MODE == 4) {
        ushort* O = Udst + (size_t)g * MAT_ELEMS;
        #pragma unroll
        for (int i = 0; i < 4; ++i)
            #pragma unroll
            for (int r = 0; r < 4; ++r) {
                size_t row = (size_t)(cm0 + i * 16 + r) * DD;
                #pragma unroll
                for (int j = 0; j < 4; ++j)
                    O[row + cn0 + j * 16] = f2b(acc[i][j][r]);
            }
    } else if (MODE == 2) {
        const ushort* C = Curp + (size_t)g * MAT_ELEMS;
        ushort* O = outU + (size_t)g * MAT_ELEMS;
        float sc = 0.5f * rsqrtf(nrm[g]);        // 0.5/nu
        #pragma unroll
        for (int i = 0; i < 4; ++i)
            #pragma unroll
            for (int r = 0; r < 4; ++r) {
                size_t row = (size_t)(cm0 + i * 16 + r) * DD;
                #pragma unroll
                for (int j = 0; j < 4; ++j) {
                    size_t off = row + cn0 + j * 16;
                    O[off] = f2b(1.5f * b2f(C[off]) - sc * acc[i][j][r]);
                }
            }
    } else {
        float* O = outF + (size_t)g * GRP_ELEMS;
        float sc = rsqrtf(sqrtf(nrm[g]));        // nu^(-1/2), nu = sqrt(nrm)
        const float* bm = bmup + g * DD;
        float bmj[4];
        #pragma unroll
        for (int j = 0; j < 4; ++j) bmj[j] = bm[cn0 + j * 16];
        #pragma unroll
        for (int i = 0; i < 4; ++i)
            #pragma unroll
            for (int r = 0; r < 4; ++r) {
                size_t row = (size_t)(cm0 + i * 16 + r) * DD;
                #pragma unroll
                for (int j = 0; j < 4; ++j)
                    O[row + cn0 + j * 16] = sc * (acc[i][j][r] - bmj[j]);
            }
    }
}

// ---------------------------------------------------------------------------
// Kernel 5: reduce split-K partials, apply mean correction (-N mu_i mu_j),
// add eps*I, emit bf16 S + per-block Frobenius^2 partial (NO atomics).
__global__ __launch_bounds__(256) void reduce_fin(const float* __restrict__ Sp,
                                                  const float* __restrict__ cs,
                                                  ushort* __restrict__ Sb,
                                                  float* __restrict__ nrmP) {
    __shared__ float wsum[4];
    int g = blockIdx.z;
    int idx = blockIdx.x * 256 + threadIdx.x;
    float v = 0.f;
    #pragma unroll
    for (int c = 0; c < KCHUNKS; ++c)
        v += Sp[(size_t)(c * NG + g) * MAT_ELEMS + idx];
    int i = idx >> 9, j = idx & 511;
    v -= (float)NN * cs[g * DD + i] * cs[g * DD + j];   // S = G - N mu mu^T
    if (i == j) v += EPSV;
    Sb[(size_t)g * MAT_ELEMS + idx] = f2b(v);
    float ss = v * v;
    #pragma unroll
    for (int o = 32; o; o >>= 1) ss += __shfl_down(ss, o, 64);
    if ((threadIdx.x & 63) == 0) wsum[threadIdx.x >> 6] = ss;
    __syncthreads();
    if (threadIdx.x == 0)
        nrmP[(size_t)g * 1024 + blockIdx.x] = wsum[0] + wsum[1] + wsum[2] + wsum[3];
}

// ---------------------------------------------------------------------------
// Kernel 5b: fold the 1024 per-block partials into nrm[g]. 4 blocks, ~2us.
__global__ __launch_bounds__(256) void nrm_fin(const float* __restrict__ nrmP,
                                               float* __restrict__ nrm) {
    __shared__ float wsum[4];
    int g = blockIdx.x;
    float s = 0.f;
    #pragma unroll
    for (int p = 0; p < 4; ++p)
        s += nrmP[(size_t)g * 1024 + p * 256 + threadIdx.x];
    #pragma unroll
    for (int o = 32; o; o >>= 1) s += __shfl_down(s, o, 64);
    if ((threadIdx.x & 63) == 0) wsum[threadIdx.x >> 6] = s;
    __syncthreads();
    if (threadIdx.x == 0) nrm[g] = wsum[0] + wsum[1] + wsum[2] + wsum[3];
}

// ---------------------------------------------------------------------------
// Kernel 6: B1 = bf16(1.5*I - 0.5*invnu*S)   (folds NS iteration 1, B0 = I)
__global__ __launch_bounds__(256) void initB_kernel(const ushort* __restrict__ Sb,
                                                    const float* __restrict__ nrm,
                                                    ushort* __restrict__ B0) {
    int g = blockIdx.z;
    int idx = blockIdx.x * 256 + threadIdx.x;
    int i = idx >> 9, j = idx & 511;
    float invnu = rsqrtf(nrm[g]);
    size_t off = (size_t)g * MAT_ELEMS + idx;
    float v = ((i == j) ? 1.5f : 0.f) - 0.5f * invnu * b2f(Sb[off]);
    B0[off] = f2b(v);
}

// ---------------------------------------------------------------------------
// Kernel 7: bmu[g][i] = sum_d B[g][i][d] * mu[g][d]  (wave-per-row, coalesced)
__global__ __launch_bounds__(256) void bmu_kernel(const ushort* __restrict__ B,
                                                  const float* __restrict__ cs,
                                                  float* __restrict__ bmu) {
    int g = blockIdx.z;
    int wave = threadIdx.x >> 6, lane = threadIdx.x & 63;
    int i = blockIdx.x * 4 + wave;
    const ushort* Bg = B + (size_t)g * MAT_ELEMS + (size_t)i * DD + lane * 8;
    const float* mu = cs + g * DD + lane * 8;
    ushort4 u0 = *(const ushort4*)(Bg);
    ushort4 u1 = *(const ushort4*)(Bg + 4);
    float s = b2f(u0.x) * mu[0] + b2f(u0.y) * mu[1]
            + b2f(u0.z) * mu[2] + b2f(u0.w) * mu[3]
            + b2f(u1.x) * mu[4] + b2f(u1.y) * mu[5]
            + b2f(u1.z) * mu[6] + b2f(u1.w) * mu[7];
    #pragma unroll
    for (int o = 32; o; o >>= 1) s += __shfl_down(s, o, 64);
    if (lane == 0) bmu[g * DD + i] = s;
}

// ---------------------------------------------------------------------------
extern "C" void kernel_launch(void* const* d_in, const int* in_sizes, int n_in,
                              void* d_out, int out_size, void* d_ws, size_t ws_size,
                              hipStream_t stream) {
    const float* Z = (const float*)d_in[0];
    float* out = (float*)d_out;
    float* ws = (float*)d_ws;

    float* cs   = ws;                        // 2048 fp32 (column MEANS)
    float* nrm  = ws + 2048;                 // 4 fp32 (padded)
    float* bmu  = ws + 2112;                 // 2048 fp32
    float* nrmP = ws + 4160;                 // 4096 fp32
    float* csP  = ws + 8256;                 // 4*64*512 = 131072 fp32
    ushort* ZbT = (ushort*)(ws + 139328);    // 64 MiB
    ushort* Zb  = ZbT + NG * GRP_ELEMS;      // 64 MiB
    float* Spart = (float*)(Zb + NG * GRP_ELEMS);  // KCHUNKS*4*MAT fp32 (16.8 MB)
    ushort* Sb = (ushort*)(Spart + (size_t)KCHUNKS * NG * MAT_ELEMS);
    ushort* B0 = Sb + NG * MAT_ELEMS;
    ushort* B1 = B0 + NG * MAT_ELEMS;
    ushort* Pb = B1 + NG * MAT_ELEMS;
    ushort* Qb = Pb + NG * MAT_ELEMS;

    // single pass over Z: both bf16 layouts + colsum partials (no memset needed)
    convT_kernel<<<dim3(64, 8, NG), 256, 0, stream>>>(Z, ZbT, Zb, csP);
    colsum_fin<<<dim3(8), 256, 0, stream>>>(csP, cs);

    // G partials: 4x (512,512,16384) syrk as gemm_bt over ZbT, split-K=4
    gemm_bt<0><<<dim3(16, KCHUNKS, NG), 256, 0, stream>>>(
        ZbT, ZbT, Spart, nullptr, nullptr, nullptr, nullptr, nullptr, nullptr,
        4, NN, NN, NN / KCHUNKS, GRP_ELEMS, GRP_ELEMS);

    reduce_fin<<<dim3(1024, 1, NG), 256, 0, stream>>>(Spart, cs, Sb, nrmP);
    nrm_fin<<<dim3(NG), 256, 0, stream>>>(nrmP, nrm);

    initB_kernel<<<dim3(1024, 1, NG), 256, 0, stream>>>(Sb, nrm, B0);

    // NS iterations 2..5. All B_t are polynomials in symmetric S~ -> commute,
    // so B^3 S = (B^2)(BS)^T with P=B^2, Q=BS INDEPENDENT -> one dual launch.
    ushort* cur = B0; ushort* nxt = B1;
    for (int it = 0; it < 4; ++it) {
        gemm_bt<4><<<dim3(32, 1, NG), 256, 0, stream>>>(
            cur, cur, nullptr, Pb, nullptr, nullptr, nullptr, Sb, Qb,
            4, DD, DD, DD, MAT_ELEMS, MAT_ELEMS);
        gemm_bt<2><<<dim3(16, 1, NG), 256, 0, stream>>>(
            Pb, Qb, nullptr, nxt, cur, nrm, nullptr, nullptr, nullptr,
            4, DD, DD, DD, MAT_ELEMS, MAT_ELEMS);
        ushort* tmp = cur; cur = nxt; nxt = tmp;
    }

    // (B mu) correction vector for the uncentered output gemm
    bmu_kernel<<<dim3(128, 1, NG), 256, 0, stream>>>(cur, cs, bmu);

    // out[g][n][i] = (Z~ . Bfinal_row_i - (B mu)_i) * nrm^(-1/4)
    gemm_bt<3><<<dim3(512, 1, NG), 256, 0, stream>>>(
        Zb, cur, out, nullptr, nullptr, nrm, bmu, nullptr, nullptr,
        128, DD, DD, DD, GRP_ELEMS, MAT_ELEMS);
}

// Round 6
// 484.230 us; speedup vs baseline: 1.6189x; 1.1008x over previous
//
#include <hip/hip_runtime.h>
#include <hip/hip_bf16.h>

// Problem: inputs (16384, 2048) fp32 -> reshape (g=4, N=16384, d=512).
#define NG 4
#define DD 512
#define NN 16384
#define EPSV 1e-5f
#define GRP_ELEMS ((size_t)NN * DD)      // 8388608 = 2^23
#define MAT_ELEMS ((size_t)DD * DD)      // 262144
#define KCHUNKS 8

typedef __attribute__((ext_vector_type(8))) short bf16x8;
typedef __attribute__((ext_vector_type(4))) float f32x4;

__device__ __forceinline__ ushort f2b(float f) {
    union { float f; unsigned u; } x; x.f = f;
    unsigned r = (x.u + 0x7fffu + ((x.u >> 16) & 1u)) >> 16;
    return (ushort)r;
}
__device__ __forceinline__ float b2f(ushort u) {
    union { unsigned u; float f; } x; x.u = ((unsigned)u) << 16;
    return x.f;
}
__device__ __forceinline__ void load_lds16(const ushort* g, ushort* l) {
    __builtin_amdgcn_global_load_lds(
        (const __attribute__((address_space(1))) void*)g,
        (__attribute__((address_space(3))) void*)l, 16, 0, 0);
}

// ---------------------------------------------------------------------------
// Kernel 1: single pass over Z. Emits UNCENTERED bf16 in both layouts and
// per-(g,nblk) column sums. Tile 256n x 64d. The LDS tile holds the data
// ALREADY transposed as packed pairs: tileT[d][np] = bf16(Z[2np]) | bf16(Z[2np+1])<<16,
// so the drain phase is vectorized b128 reads -> 512B contiguous ZbT runs.
__global__ __launch_bounds__(256) void convT_kernel(const float* __restrict__ Z,
                                                    ushort* __restrict__ ZbT,
                                                    ushort* __restrict__ Zb,
                                                    float* __restrict__ csP) {
    __shared__ __align__(16) unsigned tileT[64][132];   // 33.8 KB, 16B-aligned rows
    int g = blockIdx.z;
    int n0 = blockIdx.x * 256;
    int d0 = blockIdx.y * 64;
    int t = threadIdx.x;
    int k4 = (t & 15) * 4;        // d-offset quad
    int q = t >> 4;               // 0..15
    const float* Zg = Z + (size_t)g * GRP_ELEMS;
    ushort* ZbG = Zb + (size_t)g * GRP_ELEMS;
    #pragma unroll
    for (int p = 0; p < 8; ++p) {
        int np = q + 16 * p;                          // n-pair index 0..127
        size_t r0 = (size_t)(n0 + 2 * np) * DD + d0 + k4;
        float4 va = *(const float4*)&Zg[r0];
        float4 vb = *(const float4*)&Zg[r0 + DD];
        ushort4 oa, ob;
        oa.x = f2b(va.x); oa.y = f2b(va.y); oa.z = f2b(va.z); oa.w = f2b(va.w);
        ob.x = f2b(vb.x); ob.y = f2b(vb.y); ob.z = f2b(vb.z); ob.w = f2b(vb.w);
        *(ushort4*)&ZbG[r0] = oa;
        *(ushort4*)&ZbG[r0 + DD] = ob;
        tileT[k4 + 0][np] = (unsigned)oa.x | ((unsigned)ob.x << 16);
        tileT[k4 + 1][np] = (unsigned)oa.y | ((unsigned)ob.y << 16);
        tileT[k4 + 2][np] = (unsigned)oa.z | ((unsigned)ob.z << 16);
        tileT[k4 + 3][np] = (unsigned)oa.w | ((unsigned)ob.w << 16);
    }
    __syncthreads();
    // drain: 64 d-rows x 512B, b128 LDS reads + 16B stores (32 lanes/row)
    ushort* Og = ZbT + (size_t)g * GRP_ELEMS;
    #pragma unroll
    for (int pp = 0; pp < 8; ++pp) {
        int ci = pp * 256 + t;
        int r = ci >> 5;                  // d row 0..63
        int c = ci & 31;                  // 16B chunk within row
        uint4 v = *(const uint4*)&tileT[r][c * 4];
        *(uint4*)&Og[(size_t)(d0 + r) * NN + n0 + c * 8] = v;
    }
    // column sums over this block's 256 rows (from bf16 tile: consistent w/ G)
    if (t < 64) {
        float s = 0.f;
        #pragma unroll 16
        for (int j = 0; j < 128; ++j) {
            unsigned u = tileT[t][j];
            s += b2f((ushort)(u & 0xffffu)) + b2f((ushort)(u >> 16));
        }
        csP[((size_t)g * 64 + blockIdx.x) * 512 + d0 + t] = s;
    }
}

// ---------------------------------------------------------------------------
// Kernel 1b: fold 64 per-nblk partials -> column MEANS cs[g*512+d].
__global__ __launch_bounds__(256) void colsum_fin(const float* __restrict__ csP,
                                                  float* __restrict__ cs) {
    int c = blockIdx.x * 256 + threadIdx.x;   // 0..2047
    int g = c >> 9, d = c & 511;
    const float* p = csP + (size_t)g * 64 * 512 + d;
    float s = 0.f;
    #pragma unroll 8
    for (int b = 0; b < 64; ++b) s += p[(size_t)b * 512];
    cs[c] = s * (1.f / (float)NN);            // store the mean
}

// ---------------------------------------------------------------------------
// Shared MFMA GEMM:  C = A * B^T, A [M][K] bf16 (lda), B [N][K] bf16 (ldb).
// 128x128 tile / workgroup, 4 waves, each wave 64x64 = 4x4 MFMA 16x16x32.
// K-loop: 2 k-steps (BK=64) per barrier pair, two independent [128][32]
// buffers per operand (keeps the 64B row stride; a [128][64] layout would be
// a 16-way bank conflict on the column-read).
// MODE 0: syrk partial   -> outF[(chunkY*NG+g)*MAT + m*512 + n]  (fp32)
// MODE 1: plain          -> outU bf16
// MODE 2: NS update      -> outU = bf16(1.5*Cur - 0.5*invnu*acc)
// MODE 3: output gemm    -> outF = (acc - bmu[col]) * nrm^(-1/4)
// MODE 4: dual gemm      -> blockIdx.x>>4 selects {B=Bp,out=outU} / {B=Bp2,out=outU2}
template<int MODE>
__global__ __launch_bounds__(256) void gemm_bt(
    const ushort* __restrict__ Ap, const ushort* __restrict__ Bp,
    float* __restrict__ outF, ushort* __restrict__ outU,
    const ushort* __restrict__ Curp, const float* __restrict__ nrm,
    const float* __restrict__ bmup,
    const ushort* __restrict__ Bp2, ushort* __restrict__ outU2,
    int Mtiles, int lda, int ldb, int K, size_t grpA, size_t grpB)
{
    __shared__ __align__(16) ushort As[2][128 * 32];   // 2 k-halves, 16 KB
    __shared__ __align__(16) ushort Bs[2][128 * 32];   // 2 k-halves, 16 KB
    const int g = blockIdx.z;
    int bx = blockIdx.x;
    int half = 0;
    if (MODE == 4) { half = bx >> 4; bx &= 15; }
    const ushort* Bsrc = (MODE == 4 && half) ? Bp2 : Bp;
    ushort* Udst = (MODE == 4 && half) ? outU2 : outU;
    const int tm = (bx % Mtiles) * 128;
    const int tn = (bx / Mtiles) * 128;
    const int kstart = blockIdx.y * K;
    const ushort* Ag = Ap + (size_t)g * grpA;
    const ushort* Bg = Bsrc + (size_t)g * grpB;
    const int t = threadIdx.x;
    const int wave = t >> 6, lane = t & 63;
    const int lr = lane >> 2;            // staging row within 16-row slab
    const int lc = (lane & 3) * 8;       // staging k offset (ushort)
    const int s0 = wave * 2;             // this wave's 2 slabs per operand
    const int qm = (wave & 1) * 64, qn = (wave >> 1) * 64;
    const int fm = lane & 15;            // fragment row
    const int fk = (lane >> 4) * 8;      // fragment k offset

    const ushort* a0p = Ag + (size_t)(tm + s0 * 16 + lr) * lda + lc;
    const ushort* a1p = Ag + (size_t)(tm + s0 * 16 + 16 + lr) * lda + lc;
    const ushort* b0p = Bg + (size_t)(tn + s0 * 16 + lr) * ldb + lc;
    const ushort* b1p = Bg + (size_t)(tn + s0 * 16 + 16 + lr) * ldb + lc;
    ushort* lA0 = &As[0][s0 * 512];
    ushort* lA1 = &As[0][s0 * 512 + 512];
    ushort* lB0 = &Bs[0][s0 * 512];
    ushort* lB1 = &Bs[0][s0 * 512 + 512];
    ushort* lA0b = &As[1][s0 * 512];
    ushort* lA1b = &As[1][s0 * 512 + 512];
    ushort* lB0b = &Bs[1][s0 * 512];
    ushort* lB1b = &Bs[1][s0 * 512 + 512];

    f32x4 acc[4][4] = {};
    for (int k0 = kstart; k0 < kstart + K; k0 += 64) {
        // stage both k-halves (8 outstanding global_load_lds, one drain)
        load_lds16(a0p + k0, lA0);
        load_lds16(a1p + k0, lA1);
        load_lds16(b0p + k0, lB0);
        load_lds16(b1p + k0, lB1);
        load_lds16(a0p + k0 + 32, lA0b);
        load_lds16(a1p + k0 + 32, lA1b);
        load_lds16(b0p + k0 + 32, lB0b);
        load_lds16(b1p + k0 + 32, lB1b);
        __syncthreads();                 // drains vmcnt -> LDS valid
        #pragma unroll
        for (int h = 0; h < 2; ++h) {
            bf16x8 af[4], bfr[4];
            #pragma unroll
            for (int i = 0; i < 4; ++i) {
                af[i]  = *(const bf16x8*)&As[h][(qm + i * 16 + fm) * 32 + fk];
                bfr[i] = *(const bf16x8*)&Bs[h][(qn + i * 16 + fm) * 32 + fk];
            }
            #pragma unroll
            for (int i = 0; i < 4; ++i)
                #pragma unroll
                for (int j = 0; j < 4; ++j)
                    acc[i][j] = __builtin_amdgcn_mfma_f32_16x16x32_bf16(
                        af[i], bfr[j], acc[i][j], 0, 0, 0);
        }
        __syncthreads();                 // LDS reuse guard
    }

    // C/D layout (m89-verified): col = lane&15, row = (lane>>4)*4 + reg
    const int cn0 = tn + qn + fm;
    const int cm0 = tm + qm + (lane >> 4) * 4;
    if (MODE == 0) {
        float* O = outF + (size_t)(blockIdx.y * NG + g) * MAT_ELEMS;
        #pragma unroll
        for (int i = 0; i < 4; ++i)
            #pragma unroll
            for (int r = 0; r < 4; ++r) {
                size_t row = (size_t)(cm0 + i * 16 + r) * DD;
                #pragma unroll
                for (int j = 0; j < 4; ++j)
                    O[row + cn0 + j * 16] = acc[i][j][r];
            }
    } else if (MODE == 1 || MODE == 4) {
        ushort* O = Udst + (size_t)g * MAT_ELEMS;
        #pragma unroll
        for (int i = 0; i < 4; ++i)
            #pragma unroll
            for (int r = 0; r < 4; ++r) {
                size_t row = (size_t)(cm0 + i * 16 + r) * DD;
                #pragma unroll
                for (int j = 0; j < 4; ++j)
                    O[row + cn0 + j * 16] = f2b(acc[i][j][r]);
            }
    } else if (MODE == 2) {
        const ushort* C = Curp + (size_t)g * MAT_ELEMS;
        ushort* O = outU + (size_t)g * MAT_ELEMS;
        float sc = 0.5f * rsqrtf(nrm[g]);        // 0.5/nu
        #pragma unroll
        for (int i = 0; i < 4; ++i)
            #pragma unroll
            for (int r = 0; r < 4; ++r) {
                size_t row = (size_t)(cm0 + i * 16 + r) * DD;
                #pragma unroll
                for (int j = 0; j < 4; ++j) {
                    size_t off = row + cn0 + j * 16;
                    O[off] = f2b(1.5f * b2f(C[off]) - sc * acc[i][j][r]);
                }
            }
    } else {
        float* O = outF + (size_t)g * GRP_ELEMS;
        float sc = rsqrtf(sqrtf(nrm[g]));        // nu^(-1/2), nu = sqrt(nrm)
        const float* bm = bmup + g * DD;
        float bmj[4];
        #pragma unroll
        for (int j = 0; j < 4; ++j) bmj[j] = bm[cn0 + j * 16];
        #pragma unroll
        for (int i = 0; i < 4; ++i)
            #pragma unroll
            for (int r = 0; r < 4; ++r) {
                size_t row = (size_t)(cm0 + i * 16 + r) * DD;
                #pragma unroll
                for (int j = 0; j < 4; ++j)
                    O[row + cn0 + j * 16] = sc * (acc[i][j][r] - bmj[j]);
            }
    }
}

// ---------------------------------------------------------------------------
// Kernel 5: reduce split-K partials, apply mean correction (-N mu_i mu_j),
// add eps*I, emit bf16 S + per-block Frobenius^2 partial (NO atomics).
__global__ __launch_bounds__(256) void reduce_fin(const float* __restrict__ Sp,
                                                  const float* __restrict__ cs,
                                                  ushort* __restrict__ Sb,
                                                  float* __restrict__ nrmP) {
    __shared__ float wsum[4];
    int g = blockIdx.z;
    int idx = blockIdx.x * 256 + threadIdx.x;
    float v = 0.f;
    #pragma unroll
    for (int c = 0; c < KCHUNKS; ++c)
        v += Sp[(size_t)(c * NG + g) * MAT_ELEMS + idx];
    int i = idx >> 9, j = idx & 511;
    v -= (float)NN * cs[g * DD + i] * cs[g * DD + j];   // S = G - N mu mu^T
    if (i == j) v += EPSV;
    Sb[(size_t)g * MAT_ELEMS + idx] = f2b(v);
    float ss = v * v;
    #pragma unroll
    for (int o = 32; o; o >>= 1) ss += __shfl_down(ss, o, 64);
    if ((threadIdx.x & 63) == 0) wsum[threadIdx.x >> 6] = ss;
    __syncthreads();
    if (threadIdx.x == 0)
        nrmP[(size_t)g * 1024 + blockIdx.x] = wsum[0] + wsum[1] + wsum[2] + wsum[3];
}

// ---------------------------------------------------------------------------
// Kernel 5b: fold the 1024 per-block partials into nrm[g]. 4 blocks, ~2us.
__global__ __launch_bounds__(256) void nrm_fin(const float* __restrict__ nrmP,
                                               float* __restrict__ nrm) {
    __shared__ float wsum[4];
    int g = blockIdx.x;
    float s = 0.f;
    #pragma unroll
    for (int p = 0; p < 4; ++p)
        s += nrmP[(size_t)g * 1024 + p * 256 + threadIdx.x];
    #pragma unroll
    for (int o = 32; o; o >>= 1) s += __shfl_down(s, o, 64);
    if ((threadIdx.x & 63) == 0) wsum[threadIdx.x >> 6] = s;
    __syncthreads();
    if (threadIdx.x == 0) nrm[g] = wsum[0] + wsum[1] + wsum[2] + wsum[3];
}

// ---------------------------------------------------------------------------
// Kernel 6: B1 = bf16(1.5*I - 0.5*invnu*S)   (folds NS iteration 1, B0 = I)
__global__ __launch_bounds__(256) void initB_kernel(const ushort* __restrict__ Sb,
                                                    const float* __restrict__ nrm,
                                                    ushort* __restrict__ B0) {
    int g = blockIdx.z;
    int idx = blockIdx.x * 256 + threadIdx.x;
    int i = idx >> 9, j = idx & 511;
    float invnu = rsqrtf(nrm[g]);
    size_t off = (size_t)g * MAT_ELEMS + idx;
    float v = ((i == j) ? 1.5f : 0.f) - 0.5f * invnu * b2f(Sb[off]);
    B0[off] = f2b(v);
}

// ---------------------------------------------------------------------------
// Kernel 7: bmu[g][i] = sum_d B[g][i][d] * mu[g][d]  (wave-per-row, coalesced)
__global__ __launch_bounds__(256) void bmu_kernel(const ushort* __restrict__ B,
                                                  const float* __restrict__ cs,
                                                  float* __restrict__ bmu) {
    int g = blockIdx.z;
    int wave = threadIdx.x >> 6, lane = threadIdx.x & 63;
    int i = blockIdx.x * 4 + wave;
    const ushort* Bg = B + (size_t)g * MAT_ELEMS + (size_t)i * DD + lane * 8;
    const float* mu = cs + g * DD + lane * 8;
    ushort4 u0 = *(const ushort4*)(Bg);
    ushort4 u1 = *(const ushort4*)(Bg + 4);
    float s = b2f(u0.x) * mu[0] + b2f(u0.y) * mu[1]
            + b2f(u0.z) * mu[2] + b2f(u0.w) * mu[3]
            + b2f(u1.x) * mu[4] + b2f(u1.y) * mu[5]
            + b2f(u1.z) * mu[6] + b2f(u1.w) * mu[7];
    #pragma unroll
    for (int o = 32; o; o >>= 1) s += __shfl_down(s, o, 64);
    if (lane == 0) bmu[g * DD + i] = s;
}

// ---------------------------------------------------------------------------
extern "C" void kernel_launch(void* const* d_in, const int* in_sizes, int n_in,
                              void* d_out, int out_size, void* d_ws, size_t ws_size,
                              hipStream_t stream) {
    const float* Z = (const float*)d_in[0];
    float* out = (float*)d_out;
    float* ws = (float*)d_ws;

    float* cs   = ws;                        // 2048 fp32 (column MEANS)
    float* nrm  = ws + 2048;                 // 4 fp32 (padded)
    float* bmu  = ws + 2112;                 // 2048 fp32
    float* nrmP = ws + 4160;                 // 4096 fp32
    float* csP  = ws + 8256;                 // 4*64*512 = 131072 fp32
    ushort* ZbT = (ushort*)(ws + 139328);    // 64 MiB
    ushort* Zb  = ZbT + NG * GRP_ELEMS;      // 64 MiB
    float* Spart = (float*)(Zb + NG * GRP_ELEMS);  // KCHUNKS*4*MAT fp32 (33.5 MB)
    ushort* Sb = (ushort*)(Spart + (size_t)KCHUNKS * NG * MAT_ELEMS);
    ushort* B0 = Sb + NG * MAT_ELEMS;
    ushort* B1 = B0 + NG * MAT_ELEMS;
    ushort* Pb = B1 + NG * MAT_ELEMS;
    ushort* Qb = Pb + NG * MAT_ELEMS;

    // single pass over Z: both bf16 layouts + colsum partials (no memset needed)
    convT_kernel<<<dim3(64, 8, NG), 256, 0, stream>>>(Z, ZbT, Zb, csP);
    colsum_fin<<<dim3(8), 256, 0, stream>>>(csP, cs);

    // G partials: 4x (512,512,16384) syrk as gemm_bt over ZbT, split-K=8
    // (512 WGs = 2 blocks/CU; KCHUNKS=4 was 1 block/CU -> MfmaUtil 13%)
    gemm_bt<0><<<dim3(16, KCHUNKS, NG), 256, 0, stream>>>(
        ZbT, ZbT, Spart, nullptr, nullptr, nullptr, nullptr, nullptr, nullptr,
        4, NN, NN, NN / KCHUNKS, GRP_ELEMS, GRP_ELEMS);

    reduce_fin<<<dim3(1024, 1, NG), 256, 0, stream>>>(Spart, cs, Sb, nrmP);
    nrm_fin<<<dim3(NG), 256, 0, stream>>>(nrmP, nrm);

    initB_kernel<<<dim3(1024, 1, NG), 256, 0, stream>>>(Sb, nrm, B0);

    // NS iterations 2..5. All B_t are polynomials in symmetric S~ -> commute,
    // so B^3 S = (B^2)(BS)^T with P=B^2, Q=BS INDEPENDENT -> one dual launch.
    ushort* cur = B0; ushort* nxt = B1;
    for (int it = 0; it < 4; ++it) {
        gemm_bt<4><<<dim3(32, 1, NG), 256, 0, stream>>>(
            cur, cur, nullptr, Pb, nullptr, nullptr, nullptr, Sb, Qb,
            4, DD, DD, DD, MAT_ELEMS, MAT_ELEMS);
        gemm_bt<2><<<dim3(16, 1, NG), 256, 0, stream>>>(
            Pb, Qb, nullptr, nxt, cur, nrm, nullptr, nullptr, nullptr,
            4, DD, DD, DD, MAT_ELEMS, MAT_ELEMS);
        ushort* tmp = cur; cur = nxt; nxt = tmp;
    }

    // (B mu) correction vector for the uncentered output gemm
    bmu_kernel<<<dim3(128, 1, NG), 256, 0, stream>>>(cur, cs, bmu);

    // out[g][n][i] = (Z~ . Bfinal_row_i - (B mu)_i) * nrm^(-1/4)
    gemm_bt<3><<<dim3(512, 1, NG), 256, 0, stream>>>(
        Zb, cur, out, nullptr, nullptr, nrm, bmu, nullptr, nullptr,
        128, DD, DD, DD, GRP_ELEMS, MAT_ELEMS);
}

// Round 9
// 484.190 us; speedup vs baseline: 1.6190x; 1.0001x over previous
//
#include <hip/hip_runtime.h>
#include <hip/hip_bf16.h>

// Problem: inputs (16384, 2048) fp32 -> reshape (g=4, N=16384, d=512).
#define NG 4
#define DD 512
#define NN 16384
#define EPSV 1e-5f
#define GRP_ELEMS ((size_t)NN * DD)      // 8388608 = 2^23
#define MAT_ELEMS ((size_t)DD * DD)      // 262144
#define KCHUNKS 8

typedef __attribute__((ext_vector_type(8))) short bf16x8;
typedef __attribute__((ext_vector_type(4))) float f32x4;

__device__ __forceinline__ ushort f2b(float f) {
    union { float f; unsigned u; } x; x.f = f;
    unsigned r = (x.u + 0x7fffu + ((x.u >> 16) & 1u)) >> 16;
    return (ushort)r;
}
__device__ __forceinline__ float b2f(ushort u) {
    union { unsigned u; float f; } x; x.u = ((unsigned)u) << 16;
    return x.f;
}
__device__ __forceinline__ void load_lds16(const ushort* g, ushort* l) {
    __builtin_amdgcn_global_load_lds(
        (const __attribute__((address_space(1))) void*)g,
        (__attribute__((address_space(3))) void*)l, 16, 0, 0);
}

// ---------------------------------------------------------------------------
// Kernel 1: single pass over Z. Emits UNCENTERED bf16 in both layouts and
// per-(g,nblk) column-sum partials. Tile 256n x 64d.
// v2: (a) all 16 float4 loads hoisted (round-6 VGPR=52 proved serial issue),
// (b) tileT column XOR-swizzle at 16B-chunk granularity: pchunk = chunk ^
// ((row>>2)&7) -> ds_write conflicts 8-way -> 2-way (free), drain reads stay
// a per-row permutation (conflict-free), 16B alignment preserved (528B rows),
// (c) column sums across all 256 threads (row=t&63, quarter=t>>6).
__global__ __launch_bounds__(256) void convT_kernel(const float* __restrict__ Z,
                                                    ushort* __restrict__ ZbT,
                                                    ushort* __restrict__ Zb,
                                                    float* __restrict__ csP) {
    __shared__ __align__(16) unsigned tileT[64][132];   // 33.8 KB, 528B rows
    int g = blockIdx.z;
    int n0 = blockIdx.x * 256;
    int d0 = blockIdx.y * 64;
    int t = threadIdx.x;
    int oct = t & 7;              // d-octet: d = d0 + oct*8 .. +7
    int nb = t >> 3;              // n-pair base 0..31
    const float* Zg = Z + (size_t)g * GRP_ELEMS;
    ushort* ZbG = Zb + (size_t)g * GRP_ELEMS;

    // phase 1a: issue ALL loads (16 outstanding float4 per thread)
    float4 va[4][2], vb[4][2];
    #pragma unroll
    for (int p = 0; p < 4; ++p) {
        int np = nb + 32 * p;
        size_t r0 = (size_t)(n0 + 2 * np) * DD + d0 + oct * 8;
        va[p][0] = *(const float4*)&Zg[r0];
        va[p][1] = *(const float4*)&Zg[r0 + 4];
        vb[p][0] = *(const float4*)&Zg[r0 + DD];
        vb[p][1] = *(const float4*)&Zg[r0 + DD + 4];
    }
    // phase 1b: convert, 16B Zb stores, swizzled LDS writes
    #pragma unroll
    for (int p = 0; p < 4; ++p) {
        int np = nb + 32 * p;
        size_t r0 = (size_t)(n0 + 2 * np) * DD + d0 + oct * 8;
        ushort ua[8], ub[8];
        #pragma unroll
        for (int j = 0; j < 4; ++j) {
            ua[j]     = f2b(va[p][0][j]);
            ua[j + 4] = f2b(va[p][1][j]);
            ub[j]     = f2b(vb[p][0][j]);
            ub[j + 4] = f2b(vb[p][1][j]);
        }
        uint4 sa, sb;
        sa.x = (unsigned)ua[0] | ((unsigned)ua[1] << 16);
        sa.y = (unsigned)ua[2] | ((unsigned)ua[3] << 16);
        sa.z = (unsigned)ua[4] | ((unsigned)ua[5] << 16);
        sa.w = (unsigned)ua[6] | ((unsigned)ua[7] << 16);
        sb.x = (unsigned)ub[0] | ((unsigned)ub[1] << 16);
        sb.y = (unsigned)ub[2] | ((unsigned)ub[3] << 16);
        sb.z = (unsigned)ub[4] | ((unsigned)ub[5] << 16);
        sb.w = (unsigned)ub[6] | ((unsigned)ub[7] << 16);
        *(uint4*)&ZbG[r0] = sa;
        *(uint4*)&ZbG[r0 + DD] = sb;
        int chunk = np >> 2, off = np & 3;
        #pragma unroll
        for (int j = 0; j < 8; ++j) {
            int r = oct * 8 + j;
            int pcol = (((chunk) ^ ((r >> 2) & 7)) << 2) | off;
            tileT[r][pcol] = (unsigned)ua[j] | ((unsigned)ub[j] << 16);
        }
    }
    __syncthreads();
    // phase 2: drain 64 d-rows x 512B, swizzled b128 reads + 16B stores
    ushort* Og = ZbT + (size_t)g * GRP_ELEMS;
    #pragma unroll
    for (int pp = 0; pp < 8; ++pp) {
        int ci = pp * 256 + t;
        int r = ci >> 5;                  // d row 0..63
        int c = ci & 31;                  // logical 16B chunk
        int pc = c ^ ((r >> 2) & 7);      // physical chunk
        uint4 v = *(const uint4*)&tileT[r][pc * 4];
        *(uint4*)&Og[(size_t)(d0 + r) * NN + n0 + c * 8] = v;
    }
    // phase 3: column sums, all 256 threads (64 rows x 4 quarters)
    {
        int row = t & 63, qt = t >> 6;
        int s = (row >> 2) & 7;
        float sum = 0.f;
        #pragma unroll
        for (int ch = 0; ch < 8; ++ch) {
            int pc = (8 * qt + ch) ^ s;
            uint4 v = *(const uint4*)&tileT[row][pc * 4];
            sum += b2f((ushort)(v.x & 0xffffu)) + b2f((ushort)(v.x >> 16))
                 + b2f((ushort)(v.y & 0xffffu)) + b2f((ushort)(v.y >> 16))
                 + b2f((ushort)(v.z & 0xffffu)) + b2f((ushort)(v.z >> 16))
                 + b2f((ushort)(v.w & 0xffffu)) + b2f((ushort)(v.w >> 16));
        }
        csP[((size_t)(g * 64 + blockIdx.x)) * 2048 + (size_t)(d0 + row) * 4 + qt] = sum;
    }
}

// ---------------------------------------------------------------------------
// Kernel 1b: fold 64 nblk x 4 quarter partials -> column MEANS cs[g*512+d].
__global__ __launch_bounds__(256) void colsum_fin(const float* __restrict__ csP,
                                                  float* __restrict__ cs) {
    int c = blockIdx.x * 256 + threadIdx.x;   // 0..2047
    int g = c >> 9, d = c & 511;
    const float4* p = (const float4*)(csP + (size_t)(g * 64) * 2048 + (size_t)d * 4);
    float s = 0.f;
    #pragma unroll 8
    for (int b = 0; b < 64; ++b) {
        float4 v = p[(size_t)b * 512];        // 512 float4 = 2048 floats stride
        s += v.x + v.y + v.z + v.w;
    }
    cs[c] = s * (1.f / (float)NN);            // store the mean
}

// ---------------------------------------------------------------------------
// Shared MFMA GEMM:  C = A * B^T, A [M][K] bf16 (lda), B [N][K] bf16 (ldb).
// 128x128 tile / workgroup, 4 waves, each wave 64x64 = 4x4 MFMA 16x16x32.
// K-loop: 2 k-steps (BK=64) per barrier pair, two independent [128][32]
// buffers per operand (keeps the 64B row stride; a [128][64] layout would be
// a 16-way bank conflict on the column-read).
// MODE 0: syrk partial   -> outF[(chunkY*NG+g)*MAT + m*512 + n]  (fp32)
// MODE 1: plain          -> outU bf16
// MODE 2: NS update      -> outU = bf16(1.5*Cur - 0.5*invnu*acc)
// MODE 3: output gemm    -> outF = (acc - bmu[col]) * nrm^(-1/4)
// MODE 4: dual gemm      -> blockIdx.x>>4 selects {B=Bp,out=outU} / {B=Bp2,out=outU2}
template<int MODE>
__global__ __launch_bounds__(256) void gemm_bt(
    const ushort* __restrict__ Ap, const ushort* __restrict__ Bp,
    float* __restrict__ outF, ushort* __restrict__ outU,
    const ushort* __restrict__ Curp, const float* __restrict__ nrm,
    const float* __restrict__ bmup,
    const ushort* __restrict__ Bp2, ushort* __restrict__ outU2,
    int Mtiles, int lda, int ldb, int K, size_t grpA, size_t grpB)
{
    __shared__ __align__(16) ushort As[2][128 * 32];   // 2 k-halves, 16 KB
    __shared__ __align__(16) ushort Bs[2][128 * 32];   // 2 k-halves, 16 KB
    const int g = blockIdx.z;
    int bx = blockIdx.x;
    int half = 0;
    if (MODE == 4) { half = bx >> 4; bx &= 15; }
    const ushort* Bsrc = (MODE == 4 && half) ? Bp2 : Bp;
    ushort* Udst = (MODE == 4 && half) ? outU2 : outU;
    const int tm = (bx % Mtiles) * 128;
    const int tn = (bx / Mtiles) * 128;
    const int kstart = blockIdx.y * K;
    const ushort* Ag = Ap + (size_t)g * grpA;
    const ushort* Bg = Bsrc + (size_t)g * grpB;
    const int t = threadIdx.x;
    const int wave = t >> 6, lane = t & 63;
    const int lr = lane >> 2;            // staging row within 16-row slab
    const int lc = (lane & 3) * 8;       // staging k offset (ushort)
    const int s0 = wave * 2;             // this wave's 2 slabs per operand
    const int qm = (wave & 1) * 64, qn = (wave >> 1) * 64;
    const int fm = lane & 15;            // fragment row
    const int fk = (lane >> 4) * 8;      // fragment k offset

    const ushort* a0p = Ag + (size_t)(tm + s0 * 16 + lr) * lda + lc;
    const ushort* a1p = Ag + (size_t)(tm + s0 * 16 + 16 + lr) * lda + lc;
    const ushort* b0p = Bg + (size_t)(tn + s0 * 16 + lr) * ldb + lc;
    const ushort* b1p = Bg + (size_t)(tn + s0 * 16 + 16 + lr) * ldb + lc;
    ushort* lA0 = &As[0][s0 * 512];
    ushort* lA1 = &As[0][s0 * 512 + 512];
    ushort* lB0 = &Bs[0][s0 * 512];
    ushort* lB1 = &Bs[0][s0 * 512 + 512];
    ushort* lA0b = &As[1][s0 * 512];
    ushort* lA1b = &As[1][s0 * 512 + 512];
    ushort* lB0b = &Bs[1][s0 * 512];
    ushort* lB1b = &Bs[1][s0 * 512 + 512];

    f32x4 acc[4][4] = {};
    for (int k0 = kstart; k0 < kstart + K; k0 += 64) {
        // stage both k-halves (8 outstanding global_load_lds, one drain)
        load_lds16(a0p + k0, lA0);
        load_lds16(a1p + k0, lA1);
        load_lds16(b0p + k0, lB0);
        load_lds16(b1p + k0, lB1);
        load_lds16(a0p + k0 + 32, lA0b);
        load_lds16(a1p + k0 + 32, lA1b);
        load_lds16(b0p + k0 + 32, lB0b);
        load_lds16(b1p + k0 + 32, lB1b);
        __syncthreads();                 // drains vmcnt -> LDS valid
        #pragma unroll
        for (int h = 0; h < 2; ++h) {
            bf16x8 af[4], bfr[4];
            #pragma unroll
            for (int i = 0; i < 4; ++i) {
                af[i]  = *(const bf16x8*)&As[h][(qm + i * 16 + fm) * 32 + fk];
                bfr[i] = *(const bf16x8*)&Bs[h][(qn + i * 16 + fm) * 32 + fk];
            }
            #pragma unroll
            for (int i = 0; i < 4; ++i)
                #pragma unroll
                for (int j = 0; j < 4; ++j)
                    acc[i][j] = __builtin_amdgcn_mfma_f32_16x16x32_bf16(
                        af[i], bfr[j], acc[i][j], 0, 0, 0);
        }
        __syncthreads();                 // LDS reuse guard
    }

    // C/D layout (m89-verified): col = lane&15, row = (lane>>4)*4 + reg
    const int cn0 = tn + qn + fm;
    const int cm0 = tm + qm + (lane >> 4) * 4;
    if (MODE == 0) {
        float* O = outF + (size_t)(blockIdx.y * NG + g) * MAT_ELEMS;
        #pragma unroll
        for (int i = 0; i < 4; ++i)
            #pragma unroll
            for (int r = 0; r < 4; ++r) {
                size_t row = (size_t)(cm0 + i * 16 + r) * DD;
                #pragma unroll
                for (int j = 0; j < 4; ++j)
                    O[row + cn0 + j * 16] = acc[i][j][r];
            }
    } else if (MODE == 1 || MODE == 4) {
        ushort* O = Udst + (size_t)g * MAT_ELEMS;
        #pragma unroll
        for (int i = 0; i < 4; ++i)
            #pragma unroll
            for (int r = 0; r < 4; ++r) {
                size_t row = (size_t)(cm0 + i * 16 + r) * DD;
                #pragma unroll
                for (int j = 0; j < 4; ++j)
                    O[row + cn0 + j * 16] = f2b(acc[i][j][r]);
            }
    } else if (MODE == 2) {
        const ushort* C = Curp + (size_t)g * MAT_ELEMS;
        ushort* O = outU + (size_t)g * MAT_ELEMS;
        float sc = 0.5f * rsqrtf(nrm[g]);        // 0.5/nu
        #pragma unroll
        for (int i = 0; i < 4; ++i)
            #pragma unroll
            for (int r = 0; r < 4; ++r) {
                size_t row = (size_t)(cm0 + i * 16 + r) * DD;
                #pragma unroll
                for (int j = 0; j < 4; ++j) {
                    size_t off = row + cn0 + j * 16;
                    O[off] = f2b(1.5f * b2f(C[off]) - sc * acc[i][j][r]);
                }
            }
    } else {
        float* O = outF + (size_t)g * GRP_ELEMS;
        float sc = rsqrtf(sqrtf(nrm[g]));        // nu^(-1/2), nu = sqrt(nrm)
        const float* bm = bmup + g * DD;
        float bmj[4];
        #pragma unroll
        for (int j = 0; j < 4; ++j) bmj[j] = bm[cn0 + j * 16];
        #pragma unroll
        for (int i = 0; i < 4; ++i)
            #pragma unroll
            for (int r = 0; r < 4; ++r) {
                size_t row = (size_t)(cm0 + i * 16 + r) * DD;
                #pragma unroll
                for (int j = 0; j < 4; ++j)
                    O[row + cn0 + j * 16] = sc * (acc[i][j][r] - bmj[j]);
            }
    }
}

// ---------------------------------------------------------------------------
// Kernel 5: reduce split-K partials, apply mean correction (-N mu_i mu_j),
// add eps*I, emit bf16 S + per-block Frobenius^2 partial (NO atomics).
__global__ __launch_bounds__(256) void reduce_fin(const float* __restrict__ Sp,
                                                  const float* __restrict__ cs,
                                                  ushort* __restrict__ Sb,
                                                  float* __restrict__ nrmP) {
    __shared__ float wsum[4];
    int g = blockIdx.z;
    int idx = blockIdx.x * 256 + threadIdx.x;
    float v = 0.f;
    #pragma unroll
    for (int c = 0; c < KCHUNKS; ++c)
        v += Sp[(size_t)(c * NG + g) * MAT_ELEMS + idx];
    int i = idx >> 9, j = idx & 511;
    v -= (float)NN * cs[g * DD + i] * cs[g * DD + j];   // S = G - N mu mu^T
    if (i == j) v += EPSV;
    Sb[(size_t)g * MAT_ELEMS + idx] = f2b(v);
    float ss = v * v;
    #pragma unroll
    for (int o = 32; o; o >>= 1) ss += __shfl_down(ss, o, 64);
    if ((threadIdx.x & 63) == 0) wsum[threadIdx.x >> 6] = ss;
    __syncthreads();
    if (threadIdx.x == 0)
        nrmP[(size_t)g * 1024 + blockIdx.x] = wsum[0] + wsum[1] + wsum[2] + wsum[3];
}

// ---------------------------------------------------------------------------
// Kernel 5b: fold the 1024 per-block partials into nrm[g]. 4 blocks, ~2us.
__global__ __launch_bounds__(256) void nrm_fin(const float* __restrict__ nrmP,
                                               float* __restrict__ nrm) {
    __shared__ float wsum[4];
    int g = blockIdx.x;
    float s = 0.f;
    #pragma unroll
    for (int p = 0; p < 4; ++p)
        s += nrmP[(size_t)g * 1024 + p * 256 + threadIdx.x];
    #pragma unroll
    for (int o = 32; o; o >>= 1) s += __shfl_down(s, o, 64);
    if ((threadIdx.x & 63) == 0) wsum[threadIdx.x >> 6] = s;
    __syncthreads();
    if (threadIdx.x == 0) nrm[g] = wsum[0] + wsum[1] + wsum[2] + wsum[3];
}

// ---------------------------------------------------------------------------
// Kernel 6: B1 = bf16(1.5*I - 0.5*invnu*S)   (folds NS iteration 1, B0 = I)
__global__ __launch_bounds__(256) void initB_kernel(const ushort* __restrict__ Sb,
                                                    const float* __restrict__ nrm,
                                                    ushort* __restrict__ B0) {
    int g = blockIdx.z;
    int idx = blockIdx.x * 256 + threadIdx.x;
    int i = idx >> 9, j = idx & 511;
    float invnu = rsqrtf(nrm[g]);
    size_t off = (size_t)g * MAT_ELEMS + idx;
    float v = ((i == j) ? 1.5f : 0.f) - 0.5f * invnu * b2f(Sb[off]);
    B0[off] = f2b(v);
}

// ---------------------------------------------------------------------------
// Kernel 7: bmu[g][i] = sum_d B[g][i][d] * mu[g][d]  (wave-per-row, coalesced)
__global__ __launch_bounds__(256) void bmu_kernel(const ushort* __restrict__ B,
                                                  const float* __restrict__ cs,
                                                  float* __restrict__ bmu) {
    int g = blockIdx.z;
    int wave = threadIdx.x >> 6, lane = threadIdx.x & 63;
    int i = blockIdx.x * 4 + wave;
    const ushort* Bg = B + (size_t)g * MAT_ELEMS + (size_t)i * DD + lane * 8;
    const float* mu = cs + g * DD + lane * 8;
    ushort4 u0 = *(const ushort4*)(Bg);
    ushort4 u1 = *(const ushort4*)(Bg + 4);
    float s = b2f(u0.x) * mu[0] + b2f(u0.y) * mu[1]
            + b2f(u0.z) * mu[2] + b2f(u0.w) * mu[3]
            + b2f(u1.x) * mu[4] + b2f(u1.y) * mu[5]
            + b2f(u1.z) * mu[6] + b2f(u1.w) * mu[7];
    #pragma unroll
    for (int o = 32; o; o >>= 1) s += __shfl_down(s, o, 64);
    if (lane == 0) bmu[g * DD + i] = s;
}

// ---------------------------------------------------------------------------
extern "C" void kernel_launch(void* const* d_in, const int* in_sizes, int n_in,
                              void* d_out, int out_size, void* d_ws, size_t ws_size,
                              hipStream_t stream) {
    const float* Z = (const float*)d_in[0];
    float* out = (float*)d_out;
    float* ws = (float*)d_ws;

    float* cs   = ws;                        // 2048 fp32 (column MEANS)
    float* nrm  = ws + 2048;                 // 4 fp32 (padded)
    float* bmu  = ws + 2112;                 // 2048 fp32
    float* nrmP = ws + 4160;                 // 4096 fp32
    float* csP  = ws + 8256;                 // 4*64*2048 = 524288 fp32 (2 MB)
    ushort* ZbT = (ushort*)(ws + 532544);    // 64 MiB
    ushort* Zb  = ZbT + NG * GRP_ELEMS;      // 64 MiB
    float* Spart = (float*)(Zb + NG * GRP_ELEMS);  // KCHUNKS*4*MAT fp32 (33.5 MB)
    ushort* Sb = (ushort*)(Spart + (size_t)KCHUNKS * NG * MAT_ELEMS);
    ushort* B0 = Sb + NG * MAT_ELEMS;
    ushort* B1 = B0 + NG * MAT_ELEMS;
    ushort* Pb = B1 + NG * MAT_ELEMS;
    ushort* Qb = Pb + NG * MAT_ELEMS;

    // single pass over Z: both bf16 layouts + colsum partials (no memset needed)
    convT_kernel<<<dim3(64, 8, NG), 256, 0, stream>>>(Z, ZbT, Zb, csP);
    colsum_fin<<<dim3(8), 256, 0, stream>>>(csP, cs);

    // G partials: 4x (512,512,16384) syrk as gemm_bt over ZbT, split-K=8
    // (512 WGs = 2 blocks/CU; KCHUNKS=4 was 1 block/CU -> MfmaUtil 13%)
    gemm_bt<0><<<dim3(16, KCHUNKS, NG), 256, 0, stream>>>(
        ZbT, ZbT, Spart, nullptr, nullptr, nullptr, nullptr, nullptr, nullptr,
        4, NN, NN, NN / KCHUNKS, GRP_ELEMS, GRP_ELEMS);

    reduce_fin<<<dim3(1024, 1, NG), 256, 0, stream>>>(Spart, cs, Sb, nrmP);
    nrm_fin<<<dim3(NG), 256, 0, stream>>>(nrmP, nrm);

    initB_kernel<<<dim3(1024, 1, NG), 256, 0, stream>>>(Sb, nrm, B0);

    // NS iterations 2..5. All B_t are polynomials in symmetric S~ -> commute,
    // so B^3 S = (B^2)(BS)^T with P=B^2, Q=BS INDEPENDENT -> one dual launch.
    ushort* cur = B0; ushort* nxt = B1;
    for (int it = 0; it < 4; ++it) {
        gemm_bt<4><<<dim3(32, 1, NG), 256, 0, stream>>>(
            cur, cur, nullptr, Pb, nullptr, nullptr, nullptr, Sb, Qb,
            4, DD, DD, DD, MAT_ELEMS, MAT_ELEMS);
        gemm_bt<2><<<dim3(16, 1, NG), 256, 0, stream>>>(
            Pb, Qb, nullptr, nxt, cur, nrm, nullptr, nullptr, nullptr,
            4, DD, DD, DD, MAT_ELEMS, MAT_ELEMS);
        ushort* tmp = cur; cur = nxt; nxt = tmp;
    }

    // (B mu) correction vector for the uncentered output gemm
    bmu_kernel<<<dim3(128, 1, NG), 256, 0, stream>>>(cur, cs, bmu);

    // out[g][n][i] = (Z~ . Bfinal_row_i - (B mu)_i) * nrm^(-1/4)
    gemm_bt<3><<<dim3(512, 1, NG), 256, 0, stream>>>(
        Zb, cur, out, nullptr, nullptr, nrm, bmu, nullptr, nullptr,
        128, DD, DD, DD, GRP_ELEMS, MAT_ELEMS);
}

// Round 11
// 474.787 us; speedup vs baseline: 1.6510x; 1.0198x over previous
//
#include <hip/hip_runtime.h>
#include <hip/hip_bf16.h>

// Problem: inputs (16384, 2048) fp32 -> reshape (g=4, N=16384, d=512).
#define NG 4
#define DD 512
#define NN 16384
#define EPSV 1e-5f
#define GRP_ELEMS ((size_t)NN * DD)      // 8388608 = 2^23
#define MAT_ELEMS ((size_t)DD * DD)      // 262144
#define KCHUNKS 8

typedef __attribute__((ext_vector_type(8))) short bf16x8;
typedef __attribute__((ext_vector_type(4))) float f32x4;

__device__ __forceinline__ ushort f2b(float f) {
    union { float f; unsigned u; } x; x.f = f;
    unsigned r = (x.u + 0x7fffu + ((x.u >> 16) & 1u)) >> 16;
    return (ushort)r;
}
__device__ __forceinline__ float b2f(ushort u) {
    union { unsigned u; float f; } x; x.u = ((unsigned)u) << 16;
    return x.f;
}
__device__ __forceinline__ void load_lds16(const ushort* g, ushort* l) {
    __builtin_amdgcn_global_load_lds(
        (const __attribute__((address_space(1))) void*)g,
        (__attribute__((address_space(3))) void*)l, 16, 0, 0);
}

// ---------------------------------------------------------------------------
// Kernel 1: single pass over Z. Emits UNCENTERED bf16 in both layouts and
// per-(g,nblk) column-sum partials. Tile 128n x 64d (v3).
// v3 vs v2 post-mortem: VGPR=52 proved hipcc re-sank the "hoisted" loads
// (latency-bound, 33% occ). Fixes: (a) 17.4KB LDS tile -> 8 blocks/CU = 100%
// occupancy (3x TLP); (b) sched_barrier(0) after the 8 float4 loads — a hard
// scheduling fence the compiler cannot sink loads across (8-deep ILP/wave).
__global__ __launch_bounds__(256) void convT_kernel(const float* __restrict__ Z,
                                                    ushort* __restrict__ ZbT,
                                                    ushort* __restrict__ Zb,
                                                    float* __restrict__ csP) {
    __shared__ __align__(16) unsigned tileT[64][68];   // 17.4 KB, 272B rows
    int g = blockIdx.z;
    int n0 = blockIdx.x * 128;
    int d0 = blockIdx.y * 64;
    int t = threadIdx.x;
    int oct = t & 7;              // d-octet: d = d0 + oct*8 .. +7
    int nb = t >> 3;              // n-pair 0..31 (round A); +32 (round B)
    const float* Zg = Z + (size_t)g * GRP_ELEMS;
    ushort* ZbG = Zb + (size_t)g * GRP_ELEMS;

    // phase 1a: ALL 8 float4 loads issued, pinned by sched_barrier
    size_t r0a = (size_t)(n0 + 2 * nb) * DD + d0 + oct * 8;
    size_t r0b = (size_t)(n0 + 2 * (nb + 32)) * DD + d0 + oct * 8;
    float4 va0 = *(const float4*)&Zg[r0a];
    float4 va1 = *(const float4*)&Zg[r0a + 4];
    float4 vb0 = *(const float4*)&Zg[r0a + DD];
    float4 vb1 = *(const float4*)&Zg[r0a + DD + 4];
    float4 wa0 = *(const float4*)&Zg[r0b];
    float4 wa1 = *(const float4*)&Zg[r0b + 4];
    float4 wb0 = *(const float4*)&Zg[r0b + DD];
    float4 wb1 = *(const float4*)&Zg[r0b + DD + 4];
    __builtin_amdgcn_sched_barrier(0);   // loads stay issued up-front

    // phase 1b: convert, 16B Zb stores, swizzled LDS writes (2-way = free)
    {
        ushort ua[8], ub[8];
        #pragma unroll
        for (int j = 0; j < 4; ++j) {
            ua[j] = f2b(va0[j]); ua[j + 4] = f2b(va1[j]);
            ub[j] = f2b(vb0[j]); ub[j + 4] = f2b(vb1[j]);
        }
        uint4 sa, sb;
        sa.x = (unsigned)ua[0] | ((unsigned)ua[1] << 16);
        sa.y = (unsigned)ua[2] | ((unsigned)ua[3] << 16);
        sa.z = (unsigned)ua[4] | ((unsigned)ua[5] << 16);
        sa.w = (unsigned)ua[6] | ((unsigned)ua[7] << 16);
        sb.x = (unsigned)ub[0] | ((unsigned)ub[1] << 16);
        sb.y = (unsigned)ub[2] | ((unsigned)ub[3] << 16);
        sb.z = (unsigned)ub[4] | ((unsigned)ub[5] << 16);
        sb.w = (unsigned)ub[6] | ((unsigned)ub[7] << 16);
        *(uint4*)&ZbG[r0a] = sa;
        *(uint4*)&ZbG[r0a + DD] = sb;
        int chunk = nb >> 2, off = nb & 3;
        #pragma unroll
        for (int j = 0; j < 8; ++j) {
            int r = oct * 8 + j;
            int pcol = (((chunk) ^ ((r >> 2) & 7)) << 2) | off;
            tileT[r][pcol] = (unsigned)ua[j] | ((unsigned)ub[j] << 16);
        }
    }
    {
        ushort ua[8], ub[8];
        #pragma unroll
        for (int j = 0; j < 4; ++j) {
            ua[j] = f2b(wa0[j]); ua[j + 4] = f2b(wa1[j]);
            ub[j] = f2b(wb0[j]); ub[j + 4] = f2b(wb1[j]);
        }
        uint4 sa, sb;
        sa.x = (unsigned)ua[0] | ((unsigned)ua[1] << 16);
        sa.y = (unsigned)ua[2] | ((unsigned)ua[3] << 16);
        sa.z = (unsigned)ua[4] | ((unsigned)ua[5] << 16);
        sa.w = (unsigned)ua[6] | ((unsigned)ua[7] << 16);
        sb.x = (unsigned)ub[0] | ((unsigned)ub[1] << 16);
        sb.y = (unsigned)ub[2] | ((unsigned)ub[3] << 16);
        sb.z = (unsigned)ub[4] | ((unsigned)ub[5] << 16);
        sb.w = (unsigned)ub[6] | ((unsigned)ub[7] << 16);
        *(uint4*)&ZbG[r0b] = sa;
        *(uint4*)&ZbG[r0b + DD] = sb;
        int np = nb + 32;
        int chunk = np >> 2, off = np & 3;
        #pragma unroll
        for (int j = 0; j < 8; ++j) {
            int r = oct * 8 + j;
            int pcol = (((chunk) ^ ((r >> 2) & 7)) << 2) | off;
            tileT[r][pcol] = (unsigned)ua[j] | ((unsigned)ub[j] << 16);
        }
    }
    __syncthreads();
    // phase 2: drain 64 d-rows x 256B, swizzled b128 reads + 16B stores
    ushort* Og = ZbT + (size_t)g * GRP_ELEMS;
    #pragma unroll
    for (int pp = 0; pp < 4; ++pp) {
        int ci = pp * 256 + t;
        int r = ci >> 4;                  // d row 0..63
        int c = ci & 15;                  // logical 16B chunk
        int pc = c ^ ((r >> 2) & 7);      // physical chunk
        uint4 v = *(const uint4*)&tileT[r][pc * 4];
        *(uint4*)&Og[(size_t)(d0 + r) * NN + n0 + c * 8] = v;
    }
    // phase 3: column sums, all 256 threads (64 rows x 4 quarters)
    {
        int row = t & 63, qt = t >> 6;
        int s = (row >> 2) & 7;
        float sum = 0.f;
        #pragma unroll
        for (int ch = 0; ch < 4; ++ch) {
            int pc = (4 * qt + ch) ^ s;
            uint4 v = *(const uint4*)&tileT[row][pc * 4];
            sum += b2f((ushort)(v.x & 0xffffu)) + b2f((ushort)(v.x >> 16))
                 + b2f((ushort)(v.y & 0xffffu)) + b2f((ushort)(v.y >> 16))
                 + b2f((ushort)(v.z & 0xffffu)) + b2f((ushort)(v.z >> 16))
                 + b2f((ushort)(v.w & 0xffffu)) + b2f((ushort)(v.w >> 16));
        }
        csP[((size_t)(g * 128 + blockIdx.x)) * 2048 + (size_t)(d0 + row) * 4 + qt] = sum;
    }
}

// ---------------------------------------------------------------------------
// Kernel 1b: fold 128 nblk x 4 quarter partials -> column MEANS cs[g*512+d].
__global__ __launch_bounds__(256) void colsum_fin(const float* __restrict__ csP,
                                                  float* __restrict__ cs) {
    int c = blockIdx.x * 256 + threadIdx.x;   // 0..2047
    int g = c >> 9, d = c & 511;
    const float4* p = (const float4*)(csP + (size_t)(g * 128) * 2048 + (size_t)d * 4);
    float s = 0.f;
    #pragma unroll 8
    for (int b = 0; b < 128; ++b) {
        float4 v = p[(size_t)b * 512];        // 512 float4 = 2048 floats stride
        s += v.x + v.y + v.z + v.w;
    }
    cs[c] = s * (1.f / (float)NN);            // store the mean
}

// ---------------------------------------------------------------------------
// Shared MFMA GEMM:  C = A * B^T, A [M][K] bf16 (lda), B [N][K] bf16 (ldb).
// 128x128 tile / workgroup, 4 waves, each wave 64x64 = 4x4 MFMA 16x16x32.
// K-loop: 2 k-steps (BK=64) per barrier pair, two independent [128][32]
// buffers per operand (keeps the 64B row stride; a [128][64] layout would be
// a 16-way bank conflict on the column-read).
// MODE 0: syrk partial   -> outF[(chunkY*NG+g)*MAT + m*512 + n]  (fp32)
// MODE 1: plain          -> outU bf16
// MODE 2: NS update      -> outU = bf16(1.5*Cur - 0.5*invnu*acc)
// MODE 3: output gemm    -> outF = (acc - bmu[col]) * nrm^(-1/4)
// MODE 4: dual gemm      -> blockIdx.x>>4 selects {B=Bp,out=outU} / {B=Bp2,out=outU2}
template<int MODE>
__global__ __launch_bounds__(256) void gemm_bt(
    const ushort* __restrict__ Ap, const ushort* __restrict__ Bp,
    float* __restrict__ outF, ushort* __restrict__ outU,
    const ushort* __restrict__ Curp, const float* __restrict__ nrm,
    const float* __restrict__ bmup,
    const ushort* __restrict__ Bp2, ushort* __restrict__ outU2,
    int Mtiles, int lda, int ldb, int K, size_t grpA, size_t grpB)
{
    __shared__ __align__(16) ushort As[2][128 * 32];   // 2 k-halves, 16 KB
    __shared__ __align__(16) ushort Bs[2][128 * 32];   // 2 k-halves, 16 KB
    const int g = blockIdx.z;
    int bx = blockIdx.x;
    int half = 0;
    if (MODE == 4) { half = bx >> 4; bx &= 15; }
    const ushort* Bsrc = (MODE == 4 && half) ? Bp2 : Bp;
    ushort* Udst = (MODE == 4 && half) ? outU2 : outU;
    const int tm = (bx % Mtiles) * 128;
    const int tn = (bx / Mtiles) * 128;
    const int kstart = blockIdx.y * K;
    const ushort* Ag = Ap + (size_t)g * grpA;
    const ushort* Bg = Bsrc + (size_t)g * grpB;
    const int t = threadIdx.x;
    const int wave = t >> 6, lane = t & 63;
    const int lr = lane >> 2;            // staging row within 16-row slab
    const int lc = (lane & 3) * 8;       // staging k offset (ushort)
    const int s0 = wave * 2;             // this wave's 2 slabs per operand
    const int qm = (wave & 1) * 64, qn = (wave >> 1) * 64;
    const int fm = lane & 15;            // fragment row
    const int fk = (lane >> 4) * 8;      // fragment k offset

    const ushort* a0p = Ag + (size_t)(tm + s0 * 16 + lr) * lda + lc;
    const ushort* a1p = Ag + (size_t)(tm + s0 * 16 + 16 + lr) * lda + lc;
    const ushort* b0p = Bg + (size_t)(tn + s0 * 16 + lr) * ldb + lc;
    const ushort* b1p = Bg + (size_t)(tn + s0 * 16 + 16 + lr) * ldb + lc;
    ushort* lA0 = &As[0][s0 * 512];
    ushort* lA1 = &As[0][s0 * 512 + 512];
    ushort* lB0 = &Bs[0][s0 * 512];
    ushort* lB1 = &Bs[0][s0 * 512 + 512];
    ushort* lA0b = &As[1][s0 * 512];
    ushort* lA1b = &As[1][s0 * 512 + 512];
    ushort* lB0b = &Bs[1][s0 * 512];
    ushort* lB1b = &Bs[1][s0 * 512 + 512];

    f32x4 acc[4][4] = {};
    for (int k0 = kstart; k0 < kstart + K; k0 += 64) {
        // stage both k-halves (8 outstanding global_load_lds, one drain)
        load_lds16(a0p + k0, lA0);
        load_lds16(a1p + k0, lA1);
        load_lds16(b0p + k0, lB0);
        load_lds16(b1p + k0, lB1);
        load_lds16(a0p + k0 + 32, lA0b);
        load_lds16(a1p + k0 + 32, lA1b);
        load_lds16(b0p + k0 + 32, lB0b);
        load_lds16(b1p + k0 + 32, lB1b);
        __syncthreads();                 // drains vmcnt -> LDS valid
        #pragma unroll
        for (int h = 0; h < 2; ++h) {
            bf16x8 af[4], bfr[4];
            #pragma unroll
            for (int i = 0; i < 4; ++i) {
                af[i]  = *(const bf16x8*)&As[h][(qm + i * 16 + fm) * 32 + fk];
                bfr[i] = *(const bf16x8*)&Bs[h][(qn + i * 16 + fm) * 32 + fk];
            }
            #pragma unroll
            for (int i = 0; i < 4; ++i)
                #pragma unroll
                for (int j = 0; j < 4; ++j)
                    acc[i][j] = __builtin_amdgcn_mfma_f32_16x16x32_bf16(
                        af[i], bfr[j], acc[i][j], 0, 0, 0);
        }
        __syncthreads();                 // LDS reuse guard
    }

    // C/D layout (m89-verified): col = lane&15, row = (lane>>4)*4 + reg
    const int cn0 = tn + qn + fm;
    const int cm0 = tm + qm + (lane >> 4) * 4;
    if (MODE == 0) {
        float* O = outF + (size_t)(blockIdx.y * NG + g) * MAT_ELEMS;
        #pragma unroll
        for (int i = 0; i < 4; ++i)
            #pragma unroll
            for (int r = 0; r < 4; ++r) {
                size_t row = (size_t)(cm0 + i * 16 + r) * DD;
                #pragma unroll
                for (int j = 0; j < 4; ++j)
                    O[row + cn0 + j * 16] = acc[i][j][r];
            }
    } else if (MODE == 1 || MODE == 4) {
        ushort* O = Udst + (size_t)g * MAT_ELEMS;
        #pragma unroll
        for (int i = 0; i < 4; ++i)
            #pragma unroll
            for (int r = 0; r < 4; ++r) {
                size_t row = (size_t)(cm0 + i * 16 + r) * DD;
                #pragma unroll
                for (int j = 0; j < 4; ++j)
                    O[row + cn0 + j * 16] = f2b(acc[i][j][r]);
            }
    } else if (MODE == 2) {
        const ushort* C = Curp + (size_t)g * MAT_ELEMS;
        ushort* O = outU + (size_t)g * MAT_ELEMS;
        float sc = 0.5f * rsqrtf(nrm[g]);        // 0.5/nu
        #pragma unroll
        for (int i = 0; i < 4; ++i)
            #pragma unroll
            for (int r = 0; r < 4; ++r) {
                size_t row = (size_t)(cm0 + i * 16 + r) * DD;
                #pragma unroll
                for (int j = 0; j < 4; ++j) {
                    size_t off = row + cn0 + j * 16;
                    O[off] = f2b(1.5f * b2f(C[off]) - sc * acc[i][j][r]);
                }
            }
    } else {
        float* O = outF + (size_t)g * GRP_ELEMS;
        float sc = rsqrtf(sqrtf(nrm[g]));        // nu^(-1/2), nu = sqrt(nrm)
        const float* bm = bmup + g * DD;
        float bmj[4];
        #pragma unroll
        for (int j = 0; j < 4; ++j) bmj[j] = bm[cn0 + j * 16];
        #pragma unroll
        for (int i = 0; i < 4; ++i)
            #pragma unroll
            for (int r = 0; r < 4; ++r) {
                size_t row = (size_t)(cm0 + i * 16 + r) * DD;
                #pragma unroll
                for (int j = 0; j < 4; ++j)
                    O[row + cn0 + j * 16] = sc * (acc[i][j][r] - bmj[j]);
            }
    }
}

// ---------------------------------------------------------------------------
// Kernel 5: reduce split-K partials, apply mean correction (-N mu_i mu_j),
// add eps*I, emit bf16 S + per-block Frobenius^2 partial (NO atomics).
__global__ __launch_bounds__(256) void reduce_fin(const float* __restrict__ Sp,
                                                  const float* __restrict__ cs,
                                                  ushort* __restrict__ Sb,
                                                  float* __restrict__ nrmP) {
    __shared__ float wsum[4];
    int g = blockIdx.z;
    int idx = blockIdx.x * 256 + threadIdx.x;
    float v = 0.f;
    #pragma unroll
    for (int c = 0; c < KCHUNKS; ++c)
        v += Sp[(size_t)(c * NG + g) * MAT_ELEMS + idx];
    int i = idx >> 9, j = idx & 511;
    v -= (float)NN * cs[g * DD + i] * cs[g * DD + j];   // S = G - N mu mu^T
    if (i == j) v += EPSV;
    Sb[(size_t)g * MAT_ELEMS + idx] = f2b(v);
    float ss = v * v;
    #pragma unroll
    for (int o = 32; o; o >>= 1) ss += __shfl_down(ss, o, 64);
    if ((threadIdx.x & 63) == 0) wsum[threadIdx.x >> 6] = ss;
    __syncthreads();
    if (threadIdx.x == 0)
        nrmP[(size_t)g * 1024 + blockIdx.x] = wsum[0] + wsum[1] + wsum[2] + wsum[3];
}

// ---------------------------------------------------------------------------
// Kernel 5b: fold the 1024 per-block partials into nrm[g]. 4 blocks, ~2us.
__global__ __launch_bounds__(256) void nrm_fin(const float* __restrict__ nrmP,
                                               float* __restrict__ nrm) {
    __shared__ float wsum[4];
    int g = blockIdx.x;
    float s = 0.f;
    #pragma unroll
    for (int p = 0; p < 4; ++p)
        s += nrmP[(size_t)g * 1024 + p * 256 + threadIdx.x];
    #pragma unroll
    for (int o = 32; o; o >>= 1) s += __shfl_down(s, o, 64);
    if ((threadIdx.x & 63) == 0) wsum[threadIdx.x >> 6] = s;
    __syncthreads();
    if (threadIdx.x == 0) nrm[g] = wsum[0] + wsum[1] + wsum[2] + wsum[3];
}

// ---------------------------------------------------------------------------
// Kernel 6: B1 = bf16(1.5*I - 0.5*invnu*S)   (folds NS iteration 1, B0 = I)
__global__ __launch_bounds__(256) void initB_kernel(const ushort* __restrict__ Sb,
                                                    const float* __restrict__ nrm,
                                                    ushort* __restrict__ B0) {
    int g = blockIdx.z;
    int idx = blockIdx.x * 256 + threadIdx.x;
    int i = idx >> 9, j = idx & 511;
    float invnu = rsqrtf(nrm[g]);
    size_t off = (size_t)g * MAT_ELEMS + idx;
    float v = ((i == j) ? 1.5f : 0.f) - 0.5f * invnu * b2f(Sb[off]);
    B0[off] = f2b(v);
}

// ---------------------------------------------------------------------------
// Kernel 7: bmu[g][i] = sum_d B[g][i][d] * mu[g][d]  (wave-per-row, coalesced)
__global__ __launch_bounds__(256) void bmu_kernel(const ushort* __restrict__ B,
                                                  const float* __restrict__ cs,
                                                  float* __restrict__ bmu) {
    int g = blockIdx.z;
    int wave = threadIdx.x >> 6, lane = threadIdx.x & 63;
    int i = blockIdx.x * 4 + wave;
    const ushort* Bg = B + (size_t)g * MAT_ELEMS + (size_t)i * DD + lane * 8;
    const float* mu = cs + g * DD + lane * 8;
    ushort4 u0 = *(const ushort4*)(Bg);
    ushort4 u1 = *(const ushort4*)(Bg + 4);
    float s = b2f(u0.x) * mu[0] + b2f(u0.y) * mu[1]
            + b2f(u0.z) * mu[2] + b2f(u0.w) * mu[3]
            + b2f(u1.x) * mu[4] + b2f(u1.y) * mu[5]
            + b2f(u1.z) * mu[6] + b2f(u1.w) * mu[7];
    #pragma unroll
    for (int o = 32; o; o >>= 1) s += __shfl_down(s, o, 64);
    if (lane == 0) bmu[g * DD + i] = s;
}

// ---------------------------------------------------------------------------
extern "C" void kernel_launch(void* const* d_in, const int* in_sizes, int n_in,
                              void* d_out, int out_size, void* d_ws, size_t ws_size,
                              hipStream_t stream) {
    const float* Z = (const float*)d_in[0];
    float* out = (float*)d_out;
    float* ws = (float*)d_ws;

    float* cs   = ws;                        // 2048 fp32 (column MEANS)
    float* nrm  = ws + 2048;                 // 4 fp32 (padded)
    float* bmu  = ws + 2112;                 // 2048 fp32
    float* nrmP = ws + 4160;                 // 4096 fp32
    float* csP  = ws + 8256;                 // 4*128*2048 = 1048576 fp32 (4 MB)
    ushort* ZbT = (ushort*)(ws + 1056832);   // 64 MiB
    ushort* Zb  = ZbT + NG * GRP_ELEMS;      // 64 MiB
    float* Spart = (float*)(Zb + NG * GRP_ELEMS);  // KCHUNKS*4*MAT fp32 (33.5 MB)
    ushort* Sb = (ushort*)(Spart + (size_t)KCHUNKS * NG * MAT_ELEMS);
    ushort* B0 = Sb + NG * MAT_ELEMS;
    ushort* B1 = B0 + NG * MAT_ELEMS;
    ushort* Pb = B1 + NG * MAT_ELEMS;
    ushort* Qb = Pb + NG * MAT_ELEMS;

    // single pass over Z: both bf16 layouts + colsum partials (no memset needed)
    convT_kernel<<<dim3(128, 8, NG), 256, 0, stream>>>(Z, ZbT, Zb, csP);
    colsum_fin<<<dim3(8), 256, 0, stream>>>(csP, cs);

    // G partials: 4x (512,512,16384) syrk as gemm_bt over ZbT, split-K=8
    // (512 WGs = 2 blocks/CU; KCHUNKS=4 was 1 block/CU -> MfmaUtil 13%)
    gemm_bt<0><<<dim3(16, KCHUNKS, NG), 256, 0, stream>>>(
        ZbT, ZbT, Spart, nullptr, nullptr, nullptr, nullptr, nullptr, nullptr,
        4, NN, NN, NN / KCHUNKS, GRP_ELEMS, GRP_ELEMS);

    reduce_fin<<<dim3(1024, 1, NG), 256, 0, stream>>>(Spart, cs, Sb, nrmP);
    nrm_fin<<<dim3(NG), 256, 0, stream>>>(nrmP, nrm);

    initB_kernel<<<dim3(1024, 1, NG), 256, 0, stream>>>(Sb, nrm, B0);

    // NS iterations 2..5. All B_t are polynomials in symmetric S~ -> commute,
    // so B^3 S = (B^2)(BS)^T with P=B^2, Q=BS INDEPENDENT -> one dual launch.
    ushort* cur = B0; ushort* nxt = B1;
    for (int it = 0; it < 4; ++it) {
        gemm_bt<4><<<dim3(32, 1, NG), 256, 0, stream>>>(
            cur, cur, nullptr, Pb, nullptr, nullptr, nullptr, Sb, Qb,
            4, DD, DD, DD, MAT_ELEMS, MAT_ELEMS);
        gemm_bt<2><<<dim3(16, 1, NG), 256, 0, stream>>>(
            Pb, Qb, nullptr, nxt, cur, nrm, nullptr, nullptr, nullptr,
            4, DD, DD, DD, MAT_ELEMS, MAT_ELEMS);
        ushort* tmp = cur; cur = nxt; nxt = tmp;
    }

    // (B mu) correction vector for the uncentered output gemm
    bmu_kernel<<<dim3(128, 1, NG), 256, 0, stream>>>(cur, cs, bmu);

    // out[g][n][i] = (Z~ . Bfinal_row_i - (B mu)_i) * nrm^(-1/4)
    gemm_bt<3><<<dim3(512, 1, NG), 256, 0, stream>>>(
        Zb, cur, out, nullptr, nullptr, nrm, bmu, nullptr, nullptr,
        128, DD, DD, DD, GRP_ELEMS, MAT_ELEMS);
}